// Round 2
// baseline (1010.213 us; speedup 1.0000x reference)
//
#include <hip/hip_runtime.h>

// FreqFusion forward, f32. Shapes fixed: B=2, C=256, CC=64, HR=128x128, LR=64x64.
// Scratch strategy: d_ws is NOT used. All intermediates live inside d_out:
//   out1 region (written last by hr_out_k) hosts chf/chf2/clf/m_hrhr/m_lrhr/g_out/k_out/mask_lr
//   out2 region (written by lr_out_k, which runs AFTER hr_out_k) hosts weights + mask_hr
#define HWH 16384   // 128*128
#define HWL 4096    // 64*64
#define WH 128
#define WL 64

// ---------------- hamming helpers (np.hamming outer products) ----------------
__device__ __forceinline__ float ham3v(int t) {
    const float h[3] = {0.08f, 1.0f, 0.08f};
    return h[t / 3] * h[t % 3];
}
__device__ __forceinline__ float ham5v(int t) {
    const float h[5] = {0.08f, 0.54f, 1.0f, 0.54f, 0.08f};
    return h[t / 5] * h[t % 5];
}

// softmax over K*K ch, *ham, renorm  ==  exp(x-max)*ham / sum(exp(x-max)*ham)
template <int K>
__device__ __forceinline__ void normalize_mask(const float* __restrict src, int stride,
                                               float* m) {
    constexpr int K2 = K * K;
    float mx = -1e30f;
#pragma unroll
    for (int k = 0; k < K2; k++) {
        m[k] = src[(size_t)k * stride];
        mx = fmaxf(mx, m[k]);
    }
    float s = 0.f;
#pragma unroll
    for (int k = 0; k < K2; k++) {
        float hv = (K == 3) ? ham3v(k) : ham5v(k);
        float e = __expf(m[k] - mx) * hv;
        m[k] = e;
        s += e;
    }
    float inv = 1.f / s;
#pragma unroll
    for (int k = 0; k < K2; k++) m[k] *= inv;
}

// ---------------- weight prep: transpose to [ci][co] (co contiguous) ----------------
// wt_hr/wt_lr: [256][64]; wtE: [64*9][32] (25 used); wtE2: [64*9][16] (9 used)
__global__ void prep_w_k(const float* __restrict Whr, const float* __restrict Wlr,
                         const float* __restrict Wenc, const float* __restrict Wenc2,
                         float* __restrict wbase) {
    int tid = blockIdx.x * blockDim.x + threadIdx.x;
    int stride = gridDim.x * blockDim.x;
    float* wt_hr = wbase;
    float* wt_lr = wbase + 16384;
    float* wtE = wbase + 32768;
    float* wtE2 = wbase + 51200;
    for (int i = tid; i < 16384; i += stride) {
        int ci = i >> 6, co = i & 63;
        wt_hr[i] = Whr[co * 256 + ci];
        wt_lr[i] = Wlr[co * 256 + ci];
    }
    for (int i = tid; i < 18432; i += stride) {
        int r = i >> 5, co = i & 31;
        int ci = r / 9, t = r % 9;
        wtE[i] = (co < 25) ? Wenc[(co * 64 + ci) * 9 + t] : 0.f;
    }
    for (int i = tid; i < 9216; i += stride) {
        int r = i >> 4, co = i & 15;
        int ci = r / 9, t = r % 9;
        wtE2[i] = (co < 9) ? Wenc2[(co * 64 + ci) * 9 + t] : 0.f;
    }
}

// ---------------- 1x1 conv: (N,256,P) -> (N,64,P), co split in halves of 32 ----------------
__global__ void conv1x1_k(const float* __restrict x, const float* __restrict wt,
                          const float* __restrict bias, float* __restrict y, int HWp, int N) {
    int lin = blockIdx.x * blockDim.x + threadIdx.x;
    int px = lin % HWp;
    int t2 = lin / HWp;
    int n = t2 % N;
    int half = t2 / N;  // 0 or 1, wave-uniform
    float acc[32];
#pragma unroll
    for (int j = 0; j < 32; j++) acc[j] = 0.f;
    const float* xb = x + (size_t)n * 256 * HWp + px;
    const float* w0 = wt + half * 32;
    for (int ci = 0; ci < 256; ci++) {
        float xv = xb[(size_t)ci * HWp];
        const float* wrow = w0 + ci * 64;
#pragma unroll
        for (int j = 0; j < 32; j++) acc[j] = fmaf(wrow[j], xv, acc[j]);
    }
#pragma unroll
    for (int j = 0; j < 32; j++) {
        int co = half * 32 + j;
        y[((size_t)(n * 64 + co)) * HWp + px] = acc[j] + bias[co];
    }
}

// ---------------- 3x3 conv pad=1: (N,64,H,W) -> (N,COUT,H,W), co chunked ----------------
template <int COUT, int CHUNK, int PAD>
__global__ void conv3x3_k(const float* __restrict x, const float* __restrict wt,
                          const float* __restrict bias, float* __restrict y, int H, int W,
                          int N) {
    int lin = blockIdx.x * blockDim.x + threadIdx.x;
    int HWp = H * W;
    int px = lin % HWp;
    int t2 = lin / HWp;
    int n = t2 % N;
    int co0 = (t2 / N) * CHUNK;  // wave-uniform
    int yy = px / W, xx = px % W;
    // hoist tap offsets / validity out of the ci loop (ci-invariant)
    int offs[9];
    bool val[9];
#pragma unroll
    for (int t = 0; t < 9; t++) {
        int sy = yy + t / 3 - 1, sx = xx + t % 3 - 1;
        bool ok = (sy >= 0 && sy < H && sx >= 0 && sx < W);
        offs[t] = ok ? sy * W + sx : 0;
        val[t] = ok;
    }
    float acc[CHUNK];
#pragma unroll
    for (int j = 0; j < CHUNK; j++) acc[j] = 0.f;
    const float* xb = x + (size_t)n * 64 * HWp;
    for (int ci = 0; ci < 64; ci++) {
        const float* xc = xb + (size_t)ci * HWp;
#pragma unroll
        for (int t = 0; t < 9; t++) {
            float xv = val[t] ? xc[offs[t]] : 0.f;
            const float* wrow = wt + (ci * 9 + t) * PAD + co0;
#pragma unroll
            for (int j = 0; j < CHUNK; j++) acc[j] = fmaf(wrow[j], xv, acc[j]);
        }
    }
#pragma unroll
    for (int j = 0; j < CHUNK; j++) {
        int co = co0 + j;
        if (co < COUT) y[((size_t)(n * COUT + co)) * HWp + px] = acc[j] + bias[co];
    }
}

// ---------------- stage D+E: chf2 = 2*chf - carafe(chf, norm(mask_hr_hr), k=3, up=1) -------
__global__ void fuse_de_k(const float* __restrict chf, const float* __restrict mask,
                          float* __restrict chf2, int N) {
    int lin = blockIdx.x * blockDim.x + threadIdx.x;
    int px = lin % HWH;
    int n = lin / HWH;
    int yy = px >> 7, xx = px & 127;
    float m[9];
    normalize_mask<3>(mask + (size_t)n * 9 * HWH + px, HWH, m);
    const float* cb = chf + (size_t)n * 64 * HWH;
    float* ob = chf2 + (size_t)n * 64 * HWH;
    int offs[9];
    float mm[9];
#pragma unroll
    for (int t = 0; t < 9; t++) {
        int sy = yy + t / 3 - 1, sx = xx + t % 3 - 1;
        bool ok = (sy >= 0 && sy < WH && sx >= 0 && sx < WH);
        offs[t] = ok ? sy * WH + sx : 0;
        mm[t] = ok ? m[t] : 0.f;
    }
    for (int c = 0; c < 64; c++) {
        const float* xc = cb + (size_t)c * HWH;
        float s = 0.f;
        float center = xc[px];
#pragma unroll
        for (int t = 0; t < 9; t++) s = fmaf(mm[t], xc[offs[t]], s);
        ob[(size_t)c * HWH + px] = 2.f * center - s;
    }
}

// ---- stage H+I: mask_lr = mask_lr_hr + carafe(g_out, norm(mask_lr_hr), k=5, up=2) ----
__global__ void fuse_hi_k(const float* __restrict mlrhr, const float* __restrict g,
                          float* __restrict mask_lr, int N) {
    int lin = blockIdx.x * blockDim.x + threadIdx.x;
    int px = lin % HWH;
    int n = lin / HWH;
    int Y = px >> 7, X = px & 127;
    int h = Y >> 1, w = X >> 1;
    const float* mb = mlrhr + (size_t)n * 25 * HWH + px;
    float m[25];
    normalize_mask<5>(mb, HWH, m);
    float acc[25];
#pragma unroll
    for (int j = 0; j < 25; j++) acc[j] = 0.f;
    const float* gb = g + (size_t)n * 25 * HWL;
    for (int k = 0; k < 25; k++) {
        int sy = h + k / 5 - 2, sx = w + k % 5 - 2;
        if (sy >= 0 && sy < WL && sx >= 0 && sx < WL) {
            int off = sy * WL + sx;
            float mk = m[k];
#pragma unroll
            for (int co = 0; co < 25; co++)
                acc[co] = fmaf(mk, gb[(size_t)co * HWL + off], acc[co]);
        }
    }
#pragma unroll
    for (int co = 0; co < 25; co++)
        mask_lr[((size_t)(n * 25 + co)) * HWH + px] = mb[(size_t)co * HWH] + acc[co];
}

// ---------------- normalize mask_lr -> out0 (== m_lo2 == mask_lr_n) ----------------
__global__ void norm25_k(const float* __restrict mask_lr, float* __restrict out0, int N) {
    int lin = blockIdx.x * blockDim.x + threadIdx.x;
    int px = lin % HWH;
    int n = lin / HWH;
    float m[25];
    normalize_mask<5>(mask_lr + (size_t)n * 25 * HWH + px, HWH, m);
#pragma unroll
    for (int k = 0; k < 25; k++) out0[((size_t)(n * 25 + k)) * HWH + px] = m[k];
}

// ---- stage L: mask_hr = mask_hr_hr + carafe(k_out, out0, k=5, up=2) ----
__global__ void fuse_l_k(const float* __restrict m_n, const float* __restrict kf,
                         const float* __restrict mhrhr, float* __restrict mask_hr, int N) {
    int lin = blockIdx.x * blockDim.x + threadIdx.x;
    int px = lin % HWH;
    int n = lin / HWH;
    int Y = px >> 7, X = px & 127;
    int h = Y >> 1, w = X >> 1;
    float m[25];
#pragma unroll
    for (int k = 0; k < 25; k++) m[k] = m_n[((size_t)(n * 25 + k)) * HWH + px];
    float acc[9];
#pragma unroll
    for (int j = 0; j < 9; j++) acc[j] = 0.f;
    const float* kb = kf + (size_t)n * 9 * HWL;
    for (int k = 0; k < 25; k++) {
        int sy = h + k / 5 - 2, sx = w + k % 5 - 2;
        if (sy >= 0 && sy < WL && sx >= 0 && sx < WL) {
            int off = sy * WL + sx;
            float mk = m[k];
#pragma unroll
            for (int co = 0; co < 9; co++)
                acc[co] = fmaf(mk, kb[(size_t)co * HWL + off], acc[co]);
        }
    }
#pragma unroll
    for (int co = 0; co < 9; co++)
        mask_hr[((size_t)(n * 9 + co)) * HWH + px] =
            mhrhr[((size_t)(n * 9 + co)) * HWH + px] + acc[co];
}

// ------------- hr_out = 2*hr - carafe(hr, norm(mask_hr), k=3, up=1) -> out1 -------------
// Runs BEFORE lr_out_k: reads mask_hr from the out2 region, writes all of out1.
__global__ void hr_out_k(const float* __restrict mask_hr, const float* __restrict hr,
                         float* __restrict out1, int N) {
    int lin = blockIdx.x * blockDim.x + threadIdx.x;
    int px = lin % HWH;
    int n = lin / HWH;
    int yy = px >> 7, xx = px & 127;
    float m[9];
    normalize_mask<3>(mask_hr + (size_t)n * 9 * HWH + px, HWH, m);
    int offs[9];
    float mm[9];
#pragma unroll
    for (int t = 0; t < 9; t++) {
        int sy = yy + t / 3 - 1, sx = xx + t % 3 - 1;
        bool ok = (sy >= 0 && sy < WH && sx >= 0 && sx < WH);
        offs[t] = ok ? sy * WH + sx : 0;
        mm[t] = ok ? m[t] : 0.f;
    }
    const float* hb = hr + (size_t)n * 256 * HWH;
    float* ob = out1 + (size_t)n * 256 * HWH + px;
    for (int c = 0; c < 256; c++) {
        const float* hc = hb + (size_t)c * HWH;
        float s = 0.f;
        float center = hc[px];
#pragma unroll
        for (int t = 0; t < 9; t++) s = fmaf(mm[t], hc[offs[t]], s);
        ob[(size_t)c * HWH] = 2.f * center - s;
    }
}

// ---------------- lr_out = carafe(lr_feat, out0, k=5, up=2) -> out2 (runs LAST) ----------
__global__ void lr_out_k(const float* __restrict m_n, const float* __restrict lr,
                         float* __restrict out2, int N) {
    int lin = blockIdx.x * blockDim.x + threadIdx.x;
    int px = lin % HWH;
    int n = lin / HWH;
    int Y = px >> 7, X = px & 127;
    int h = Y >> 1, w = X >> 1;
    float mm[25];
    int offs[25];
#pragma unroll
    for (int k = 0; k < 25; k++) {
        float mk = m_n[((size_t)(n * 25 + k)) * HWH + px];
        int sy = h + k / 5 - 2, sx = w + k % 5 - 2;
        bool ok = (sy >= 0 && sy < WL && sx >= 0 && sx < WL);
        offs[k] = ok ? sy * WL + sx : 0;
        mm[k] = ok ? mk : 0.f;
    }
    const float* lb = lr + (size_t)n * 256 * HWL;
    float* ob = out2 + (size_t)n * 256 * HWH + px;
    for (int c = 0; c < 256; c++) {
        const float* lc = lb + (size_t)c * HWL;
        float s = 0.f;
#pragma unroll
        for (int k = 0; k < 25; k++) s = fmaf(mm[k], lc[offs[k]], s);
        ob[(size_t)c * HWH] = s;
    }
}

extern "C" void kernel_launch(void* const* d_in, const int* in_sizes, int n_in, void* d_out,
                              int out_size, void* d_ws, size_t ws_size, hipStream_t stream) {
    const float* hr = (const float*)d_in[0];
    const float* lr = (const float*)d_in[1];
    const float* Whr = (const float*)d_in[2];
    const float* bhr = (const float*)d_in[3];
    const float* Wlr = (const float*)d_in[4];
    const float* blr = (const float*)d_in[5];
    const float* Wenc = (const float*)d_in[6];
    const float* benc = (const float*)d_in[7];
    const float* Wenc2 = (const float*)d_in[8];
    const float* benc2 = (const float*)d_in[9];
    float* out = (float*)d_out;
    const int B = in_sizes[0] / (256 * HWH);  // 2
    (void)d_ws; (void)ws_size;

    float* out0 = out;                           // B*25*HWH  (final: mask_lr_n)
    float* O1 = out + (size_t)B * 25 * HWH;      // B*256*HWH (final: hr_out)
    float* O2 = O1 + (size_t)B * 256 * HWH;      // B*256*HWH (final: lr_out)

    // --- scratch inside O2 (dead before lr_out_k overwrites O2) ---
    float* wbase = O2;                                // 60416 floats of weights
    float* wt_hr = wbase;                             // 16384
    float* wt_lr = wbase + 16384;                     // 16384
    float* wtE = wbase + 32768;                       // 18432
    float* wtE2 = wbase + 51200;                      // 9216
    float* mask_hr = O2 + 60416;                      // B*9*HWH = 294912 (ends 355328)

    // --- scratch inside O1 (dead before hr_out_k overwrites O1) ---
    float* chf = O1;                                  // B*64*HWH = 2097152
    float* chf2 = chf + (size_t)B * 64 * HWH;         // 2097152
    float* clf = chf2 + (size_t)B * 64 * HWH;         // B*64*HWL = 524288
    float* m_hrhr = clf + (size_t)B * 64 * HWL;       // B*9*HWH = 294912
    float* m_lrhr = m_hrhr + (size_t)B * 9 * HWH;     // B*25*HWH = 819200
    float* g_out = m_lrhr + (size_t)B * 25 * HWH;     // B*25*HWL = 204800
    float* k_out = g_out + (size_t)B * 25 * HWL;      // B*9*HWL = 73728
    float* mask_lr = k_out + (size_t)B * 9 * HWL;     // B*25*HWH (ends 6930432 < B*256*HWH)

    prep_w_k<<<64, 256, 0, stream>>>(Whr, Wlr, Wenc, Wenc2, wbase);
    // A/B: 1x1 convs
    conv1x1_k<<<B * HWH * 2 / 256, 256, 0, stream>>>(hr, wt_hr, bhr, chf, HWH, B);
    conv1x1_k<<<B * HWL * 2 / 256, 256, 0, stream>>>(lr, wt_lr, blr, clf, HWL, B);
    // C: 3x3 chf -> mask_hr_hr (9ch)
    conv3x3_k<9, 5, 16><<<B * HWH * 2 / 256, 256, 0, stream>>>(chf, wtE2, benc2, m_hrhr,
                                                               WH, WH, B);
    // D+E: chf2
    fuse_de_k<<<B * HWH / 256, 256, 0, stream>>>(chf, m_hrhr, chf2, B);
    // F: 3x3 chf2 -> mask_lr_hr (25ch)
    conv3x3_k<25, 13, 32><<<B * HWH * 2 / 256, 256, 0, stream>>>(chf2, wtE, benc, m_lrhr,
                                                                 WH, WH, B);
    // G/K: 3x3 on clf
    conv3x3_k<25, 7, 32><<<B * HWL * 4 / 256, 256, 0, stream>>>(clf, wtE, benc, g_out, WL,
                                                                WL, B);
    conv3x3_k<9, 3, 16><<<B * HWL * 3 / 256, 256, 0, stream>>>(clf, wtE2, benc2, k_out, WL,
                                                               WL, B);
    // H+I: mask_lr
    fuse_hi_k<<<B * HWH / 256, 256, 0, stream>>>(m_lrhr, g_out, mask_lr, B);
    // J: out0 = normalize(mask_lr)  (== m_lo2 == mask_lr_n)
    norm25_k<<<B * HWH / 256, 256, 0, stream>>>(mask_lr, out0, B);
    // L: mask_hr (lives in O2 scratch)
    fuse_l_k<<<B * HWH / 256, 256, 0, stream>>>(out0, k_out, m_hrhr, mask_hr, B);
    // M+O: hr_out -> O1 (overwrites all O1 scratch; reads only O2 scratch + hr)
    hr_out_k<<<B * HWH / 256, 256, 0, stream>>>(mask_hr, hr, O1, B);
    // N: lr_out -> O2 (overwrites weights + mask_hr scratch; reads out0 + lr)
    lr_out_k<<<B * HWH / 256, 256, 0, stream>>>(out0, lr, O2, B);
}

// Round 3
// 439.534 us; speedup vs baseline: 2.2984x; 2.2984x over previous
//
#include <hip/hip_runtime.h>

// FreqFusion forward, f32. Shapes fixed: B=2, C=256, CC=64, HR=128x128, LR=64x64.
// Scratch strategy: d_ws is NOT used. All intermediates live inside d_out:
//   O1 region (written last-but-one by hr_out_k) hosts chf/chf2/clf/m_hrhr/m_lrhr/g_out/k_out/mask_lr
//   O2 region (written last by lr_out_k) hosts transposed weights + mask_hr
#define HWH 16384   // 128*128
#define HWL 4096    // 64*64
#define WH 128
#define WL 64

// ---------------- hamming helpers (np.hamming outer products) ----------------
__device__ __forceinline__ float ham3v(int t) {
    const float h[3] = {0.08f, 1.0f, 0.08f};
    return h[t / 3] * h[t % 3];
}
__device__ __forceinline__ float ham5v(int t) {
    const float h[5] = {0.08f, 0.54f, 1.0f, 0.54f, 0.08f};
    return h[t / 5] * h[t % 5];
}

// softmax over K*K ch, *ham, renorm  ==  exp(x-max)*ham / sum(exp(x-max)*ham)
template <int K>
__device__ __forceinline__ void normalize_mask(const float* __restrict src, int stride,
                                               float* m) {
    constexpr int K2 = K * K;
    float mx = -1e30f;
#pragma unroll
    for (int k = 0; k < K2; k++) {
        m[k] = src[(size_t)k * stride];
        mx = fmaxf(mx, m[k]);
    }
    float s = 0.f;
#pragma unroll
    for (int k = 0; k < K2; k++) {
        float hv = (K == 3) ? ham3v(k) : ham5v(k);
        float e = __expf(m[k] - mx) * hv;
        m[k] = e;
        s += e;
    }
    float inv = 1.f / s;
#pragma unroll
    for (int k = 0; k < K2; k++) m[k] *= inv;
}

// ---------------- weight prep: transpose to [ci][co] (co contiguous) ----------------
__global__ void prep_w_k(const float* __restrict Whr, const float* __restrict Wlr,
                         const float* __restrict Wenc, const float* __restrict Wenc2,
                         float* __restrict wbase) {
    int tid = blockIdx.x * blockDim.x + threadIdx.x;
    int stride = gridDim.x * blockDim.x;
    float* wt_hr = wbase;
    float* wt_lr = wbase + 16384;
    float* wtE = wbase + 32768;
    float* wtE2 = wbase + 51200;
    for (int i = tid; i < 16384; i += stride) {
        int ci = i >> 6, co = i & 63;
        wt_hr[i] = Whr[co * 256 + ci];
        wt_lr[i] = Wlr[co * 256 + ci];
    }
    for (int i = tid; i < 18432; i += stride) {
        int r = i >> 5, co = i & 31;
        int ci = r / 9, t = r % 9;
        wtE[i] = (co < 25) ? Wenc[(co * 64 + ci) * 9 + t] : 0.f;
    }
    for (int i = tid; i < 9216; i += stride) {
        int r = i >> 4, co = i & 15;
        int ci = r / 9, t = r % 9;
        wtE2[i] = (co < 9) ? Wenc2[(co * 64 + ci) * 9 + t] : 0.f;
    }
}

// ------------- 1x1 conv: (N,256,P) -> (N,64,P), co split into 64/CHUNK groups -------------
template <int CHUNK>
__global__ void conv1x1_k(const float* __restrict x, const float* __restrict wt,
                          const float* __restrict bias, float* __restrict y, int HWp, int N) {
    int lin = blockIdx.x * blockDim.x + threadIdx.x;
    int px = lin % HWp;
    int t2 = lin / HWp;
    int n = t2 % N;
    int co0 = (t2 / N) * CHUNK;  // wave-uniform
    float acc[CHUNK];
#pragma unroll
    for (int j = 0; j < CHUNK; j++) acc[j] = 0.f;
    const float* xb = x + (size_t)n * 256 * HWp + px;
    const float* w0 = wt + co0;
    for (int ci = 0; ci < 256; ci++) {
        float xv = xb[(size_t)ci * HWp];
        const float* wrow = w0 + ci * 64;
#pragma unroll
        for (int j = 0; j < CHUNK; j++) acc[j] = fmaf(wrow[j], xv, acc[j]);
    }
#pragma unroll
    for (int j = 0; j < CHUNK; j++) {
        int co = co0 + j;
        y[((size_t)(n * 64 + co)) * HWp + px] = acc[j] + bias[co];
    }
}

// ---------------- 3x3 conv pad=1: (N,64,H,W) -> (N,COUT,H,W), co chunked ----------------
template <int COUT, int CHUNK, int PAD>
__global__ void conv3x3_k(const float* __restrict x, const float* __restrict wt,
                          const float* __restrict bias, float* __restrict y, int H, int W,
                          int N) {
    int lin = blockIdx.x * blockDim.x + threadIdx.x;
    int HWp = H * W;
    int px = lin % HWp;
    int t2 = lin / HWp;
    int n = t2 % N;
    int co0 = (t2 / N) * CHUNK;  // wave-uniform
    int yy = px / W, xx = px % W;
    int offs[9];
    bool val[9];
#pragma unroll
    for (int t = 0; t < 9; t++) {
        int sy = yy + t / 3 - 1, sx = xx + t % 3 - 1;
        bool ok = (sy >= 0 && sy < H && sx >= 0 && sx < W);
        offs[t] = ok ? sy * W + sx : 0;
        val[t] = ok;
    }
    float acc[CHUNK];
#pragma unroll
    for (int j = 0; j < CHUNK; j++) acc[j] = 0.f;
    const float* xb = x + (size_t)n * 64 * HWp;
    for (int ci = 0; ci < 64; ci++) {
        const float* xc = xb + (size_t)ci * HWp;
#pragma unroll
        for (int t = 0; t < 9; t++) {
            float xv = val[t] ? xc[offs[t]] : 0.f;
            const float* wrow = wt + (ci * 9 + t) * PAD + co0;
#pragma unroll
            for (int j = 0; j < CHUNK; j++) acc[j] = fmaf(wrow[j], xv, acc[j]);
        }
    }
#pragma unroll
    for (int j = 0; j < CHUNK; j++) {
        int co = co0 + j;
        if (co < COUT) y[((size_t)(n * COUT + co)) * HWp + px] = acc[j] + bias[co];
    }
}

// ------- stage D+E: chf2 = 2*chf - carafe(chf, norm(mask_hr_hr), k=3, up=1) -------
// channel-split: NCG groups of 64/NCG channels
template <int NCG>
__global__ void fuse_de_k(const float* __restrict chf, const float* __restrict mask,
                          float* __restrict chf2, int N) {
    constexpr int NCH = 64 / NCG;
    int lin = blockIdx.x * blockDim.x + threadIdx.x;
    int px = lin % HWH;
    int rest = lin / HWH;
    int n = rest % N;
    int c0 = (rest / N) * NCH;
    int yy = px >> 7, xx = px & 127;
    float m[9];
    normalize_mask<3>(mask + (size_t)n * 9 * HWH + px, HWH, m);
    int offs[9];
    float mm[9];
#pragma unroll
    for (int t = 0; t < 9; t++) {
        int sy = yy + t / 3 - 1, sx = xx + t % 3 - 1;
        bool ok = (sy >= 0 && sy < WH && sx >= 0 && sx < WH);
        offs[t] = ok ? sy * WH + sx : 0;
        mm[t] = ok ? m[t] : 0.f;
    }
    const float* cb = chf + (size_t)n * 64 * HWH;
    float* ob = chf2 + (size_t)n * 64 * HWH + px;
    for (int c = c0; c < c0 + NCH; c++) {
        const float* xc = cb + (size_t)c * HWH;
        float s = 0.f;
        float center = 0.f;
#pragma unroll
        for (int t = 0; t < 9; t++) {
            float xv = xc[offs[t]];
            if (t == 4) center = xv;
            s = fmaf(mm[t], xv, s);
        }
        ob[(size_t)c * HWH] = 2.f * center - s;
    }
}

// ---- stage H+I: mask_lr = mask_lr_hr + carafe(g_out, norm(mask_lr_hr), k=5, up=2) ----
// co split into 5 groups of 5
__global__ void fuse_hi_k(const float* __restrict mlrhr, const float* __restrict g,
                          float* __restrict mask_lr, int N) {
    int lin = blockIdx.x * blockDim.x + threadIdx.x;
    int px = lin % HWH;
    int rest = lin / HWH;
    int n = rest % N;
    int co0 = (rest / N) * 5;
    int Y = px >> 7, X = px & 127;
    int h = Y >> 1, w = X >> 1;
    const float* mb = mlrhr + (size_t)n * 25 * HWH + px;
    float m[25];
    normalize_mask<5>(mb, HWH, m);
    float acc[5];
#pragma unroll
    for (int j = 0; j < 5; j++) acc[j] = 0.f;
    const float* gb = g + ((size_t)n * 25 + co0) * HWL;
    for (int k = 0; k < 25; k++) {
        int sy = h + k / 5 - 2, sx = w + k % 5 - 2;
        if (sy >= 0 && sy < WL && sx >= 0 && sx < WL) {
            int off = sy * WL + sx;
            float mk = m[k];
#pragma unroll
            for (int j = 0; j < 5; j++)
                acc[j] = fmaf(mk, gb[(size_t)j * HWL + off], acc[j]);
        }
    }
#pragma unroll
    for (int j = 0; j < 5; j++)
        mask_lr[((size_t)(n * 25 + co0 + j)) * HWH + px] =
            mb[(size_t)(co0 + j) * HWH] + acc[j];
}

// ---------------- normalize mask_lr -> out0 (== m_lo2 == mask_lr_n) ----------------
__global__ void norm25_k(const float* __restrict mask_lr, float* __restrict out0, int N) {
    int lin = blockIdx.x * blockDim.x + threadIdx.x;
    int px = lin % HWH;
    int n = lin / HWH;
    float m[25];
    normalize_mask<5>(mask_lr + (size_t)n * 25 * HWH + px, HWH, m);
#pragma unroll
    for (int k = 0; k < 25; k++) out0[((size_t)(n * 25 + k)) * HWH + px] = m[k];
}

// ---- stage L: mask_hr = mask_hr_hr + carafe(k_out, out0, k=5, up=2); co in 3 groups of 3 ----
__global__ void fuse_l_k(const float* __restrict m_n, const float* __restrict kf,
                         const float* __restrict mhrhr, float* __restrict mask_hr, int N) {
    int lin = blockIdx.x * blockDim.x + threadIdx.x;
    int px = lin % HWH;
    int rest = lin / HWH;
    int n = rest % N;
    int co0 = (rest / N) * 3;
    int Y = px >> 7, X = px & 127;
    int h = Y >> 1, w = X >> 1;
    float m[25];
#pragma unroll
    for (int k = 0; k < 25; k++) m[k] = m_n[((size_t)(n * 25 + k)) * HWH + px];
    float acc[3];
#pragma unroll
    for (int j = 0; j < 3; j++) acc[j] = 0.f;
    const float* kb = kf + ((size_t)n * 9 + co0) * HWL;
    for (int k = 0; k < 25; k++) {
        int sy = h + k / 5 - 2, sx = w + k % 5 - 2;
        if (sy >= 0 && sy < WL && sx >= 0 && sx < WL) {
            int off = sy * WL + sx;
            float mk = m[k];
#pragma unroll
            for (int j = 0; j < 3; j++)
                acc[j] = fmaf(mk, kb[(size_t)j * HWL + off], acc[j]);
        }
    }
#pragma unroll
    for (int j = 0; j < 3; j++)
        mask_hr[((size_t)(n * 9 + co0 + j)) * HWH + px] =
            mhrhr[((size_t)(n * 9 + co0 + j)) * HWH + px] + acc[j];
}

// ------------- hr_out = 2*hr - carafe(hr, norm(mask_hr), k=3, up=1) -> out1 -------------
// channel-split NCG groups of 256/NCG; runs BEFORE lr_out_k (reads mask_hr in O2 scratch)
template <int NCG>
__global__ void hr_out_k(const float* __restrict mask_hr, const float* __restrict hr,
                         float* __restrict out1, int N) {
    constexpr int NCH = 256 / NCG;
    int lin = blockIdx.x * blockDim.x + threadIdx.x;
    int px = lin % HWH;
    int rest = lin / HWH;
    int n = rest % N;
    int c0 = (rest / N) * NCH;
    int yy = px >> 7, xx = px & 127;
    float m[9];
    normalize_mask<3>(mask_hr + (size_t)n * 9 * HWH + px, HWH, m);
    int offs[9];
    float mm[9];
#pragma unroll
    for (int t = 0; t < 9; t++) {
        int sy = yy + t / 3 - 1, sx = xx + t % 3 - 1;
        bool ok = (sy >= 0 && sy < WH && sx >= 0 && sx < WH);
        offs[t] = ok ? sy * WH + sx : 0;
        mm[t] = ok ? m[t] : 0.f;
    }
    const float* hb = hr + (size_t)n * 256 * HWH;
    float* ob = out1 + (size_t)n * 256 * HWH + px;
    for (int c = c0; c < c0 + NCH; c++) {
        const float* hc = hb + (size_t)c * HWH;
        float s = 0.f;
        float center = 0.f;
#pragma unroll
        for (int t = 0; t < 9; t++) {
            float xv = hc[offs[t]];
            if (t == 4) center = xv;
            s = fmaf(mm[t], xv, s);
        }
        ob[(size_t)c * HWH] = 2.f * center - s;
    }
}

// ------- lr_out = carafe(lr_feat, out0, k=5, up=2) -> out2 (runs LAST); channel-split -------
template <int NCG>
__global__ void lr_out_k(const float* __restrict m_n, const float* __restrict lr,
                         float* __restrict out2, int N) {
    constexpr int NCH = 256 / NCG;
    int lin = blockIdx.x * blockDim.x + threadIdx.x;
    int px = lin % HWH;
    int rest = lin / HWH;
    int n = rest % N;
    int c0 = (rest / N) * NCH;
    int Y = px >> 7, X = px & 127;
    int h = Y >> 1, w = X >> 1;
    float mm[25];
    int offs[25];
#pragma unroll
    for (int k = 0; k < 25; k++) {
        float mk = m_n[((size_t)(n * 25 + k)) * HWH + px];
        int sy = h + k / 5 - 2, sx = w + k % 5 - 2;
        bool ok = (sy >= 0 && sy < WL && sx >= 0 && sx < WL);
        offs[k] = ok ? sy * WL + sx : 0;
        mm[k] = ok ? mk : 0.f;
    }
    const float* lb = lr + (size_t)n * 256 * HWL;
    float* ob = out2 + (size_t)n * 256 * HWH + px;
    for (int c = c0; c < c0 + NCH; c++) {
        const float* lc = lb + (size_t)c * HWL;
        float s = 0.f;
#pragma unroll
        for (int k = 0; k < 25; k++) s = fmaf(mm[k], lc[offs[k]], s);
        ob[(size_t)c * HWH] = s;
    }
}

extern "C" void kernel_launch(void* const* d_in, const int* in_sizes, int n_in, void* d_out,
                              int out_size, void* d_ws, size_t ws_size, hipStream_t stream) {
    const float* hr = (const float*)d_in[0];
    const float* lr = (const float*)d_in[1];
    const float* Whr = (const float*)d_in[2];
    const float* bhr = (const float*)d_in[3];
    const float* Wlr = (const float*)d_in[4];
    const float* blr = (const float*)d_in[5];
    const float* Wenc = (const float*)d_in[6];
    const float* benc = (const float*)d_in[7];
    const float* Wenc2 = (const float*)d_in[8];
    const float* benc2 = (const float*)d_in[9];
    float* out = (float*)d_out;
    const int B = in_sizes[0] / (256 * HWH);  // 2
    (void)d_ws; (void)ws_size;

    float* out0 = out;                           // B*25*HWH  (final: mask_lr_n)
    float* O1 = out + (size_t)B * 25 * HWH;      // B*256*HWH (final: hr_out)
    float* O2 = O1 + (size_t)B * 256 * HWH;      // B*256*HWH (final: lr_out)

    // --- scratch inside O2 (dead before lr_out_k overwrites O2) ---
    float* wbase = O2;                                // 60416 floats of weights
    float* wt_hr = wbase;                             // 16384
    float* wt_lr = wbase + 16384;                     // 16384
    float* wtE = wbase + 32768;                       // 18432
    float* wtE2 = wbase + 51200;                      // 9216
    float* mask_hr = O2 + 60416;                      // B*9*HWH = 294912

    // --- scratch inside O1 (dead before hr_out_k overwrites O1) ---
    float* chf = O1;                                  // B*64*HWH = 2097152
    float* chf2 = chf + (size_t)B * 64 * HWH;         // 2097152
    float* clf = chf2 + (size_t)B * 64 * HWH;         // B*64*HWL = 524288
    float* m_hrhr = clf + (size_t)B * 64 * HWL;       // B*9*HWH = 294912
    float* m_lrhr = m_hrhr + (size_t)B * 9 * HWH;     // B*25*HWH = 819200
    float* g_out = m_lrhr + (size_t)B * 25 * HWH;     // B*25*HWL = 204800
    float* k_out = g_out + (size_t)B * 25 * HWL;      // B*9*HWL = 73728
    float* mask_lr = k_out + (size_t)B * 9 * HWL;     // B*25*HWH (ends 6930432 < 8388608)

    prep_w_k<<<64, 256, 0, stream>>>(Whr, Wlr, Wenc, Wenc2, wbase);
    // A/B: 1x1 convs (co quarters / eighths)
    conv1x1_k<16><<<B * HWH * 4 / 256, 256, 0, stream>>>(hr, wt_hr, bhr, chf, HWH, B);
    conv1x1_k<8><<<B * HWL * 8 / 256, 256, 0, stream>>>(lr, wt_lr, blr, clf, HWL, B);
    // C: 3x3 chf -> mask_hr_hr (9ch, 3 groups)
    conv3x3_k<9, 3, 16><<<B * HWH * 3 / 256, 256, 0, stream>>>(chf, wtE2, benc2, m_hrhr,
                                                               WH, WH, B);
    // D+E: chf2 (8 channel-groups)
    fuse_de_k<8><<<B * HWH * 8 / 256, 256, 0, stream>>>(chf, m_hrhr, chf2, B);
    // F: 3x3 chf2 -> mask_lr_hr (25ch, 5 groups)
    conv3x3_k<25, 5, 32><<<B * HWH * 5 / 256, 256, 0, stream>>>(chf2, wtE, benc, m_lrhr,
                                                                WH, WH, B);
    // G/K: 3x3 on clf
    conv3x3_k<25, 5, 32><<<B * HWL * 5 / 256, 256, 0, stream>>>(clf, wtE, benc, g_out, WL,
                                                                WL, B);
    conv3x3_k<9, 3, 16><<<B * HWL * 3 / 256, 256, 0, stream>>>(clf, wtE2, benc2, k_out, WL,
                                                               WL, B);
    // H+I: mask_lr (5 co-groups)
    fuse_hi_k<<<B * HWH * 5 / 256, 256, 0, stream>>>(m_lrhr, g_out, mask_lr, B);
    // J: out0 = normalize(mask_lr)  (== m_lo2 == mask_lr_n)
    norm25_k<<<B * HWH / 256, 256, 0, stream>>>(mask_lr, out0, B);
    // L: mask_hr (3 co-groups; lives in O2 scratch)
    fuse_l_k<<<B * HWH * 3 / 256, 256, 0, stream>>>(out0, k_out, m_hrhr, mask_hr, B);
    // M+O: hr_out -> O1 (16 channel-groups)
    hr_out_k<16><<<B * HWH * 16 / 256, 256, 0, stream>>>(mask_hr, hr, O1, B);
    // N: lr_out -> O2 (16 channel-groups)
    lr_out_k<16><<<B * HWH * 16 / 256, 256, 0, stream>>>(out0, lr, O2, B);
}

// Round 4
// 365.089 us; speedup vs baseline: 2.7670x; 1.2039x over previous
//
#include <hip/hip_runtime.h>

// FreqFusion forward, f32. Shapes fixed: B=2, C=256, CC=64, HR=128x128, LR=64x64.
// Scratch: d_ws unused. Intermediates live inside d_out (see layout in kernel_launch).
#define HWH 16384   // 128*128
#define HWL 4096    // 64*64
#define WH 128
#define WL 64

// ---------------- hamming helpers ----------------
__device__ __forceinline__ float ham3v(int t) {
    const float h[3] = {0.08f, 1.0f, 0.08f};
    return h[t / 3] * h[t % 3];
}
__device__ __forceinline__ float ham5v(int t) {
    const float h[5] = {0.08f, 0.54f, 1.0f, 0.54f, 0.08f};
    return h[t / 5] * h[t % 5];
}

// softmax over K*K ch, *ham, renorm  ==  exp(x-max)*ham / sum(exp(x-max)*ham)
template <int K>
__device__ __forceinline__ void normalize_mask(const float* __restrict src, int stride,
                                               float* m) {
    constexpr int K2 = K * K;
    float mx = -1e30f;
#pragma unroll
    for (int k = 0; k < K2; k++) {
        m[k] = src[(size_t)k * stride];
        mx = fmaxf(mx, m[k]);
    }
    float s = 0.f;
#pragma unroll
    for (int k = 0; k < K2; k++) {
        float hv = (K == 3) ? ham3v(k) : ham5v(k);
        float e = __expf(m[k] - mx) * hv;
        m[k] = e;
        s += e;
    }
    float inv = 1.f / s;
#pragma unroll
    for (int k = 0; k < K2; k++) m[k] *= inv;
}

// ---------------- weight prep: transpose to [ci][co] (co contiguous) ----------------
__global__ void prep_w_k(const float* __restrict Whr, const float* __restrict Wlr,
                         const float* __restrict Wenc, const float* __restrict Wenc2,
                         float* __restrict wbase) {
    int tid = blockIdx.x * blockDim.x + threadIdx.x;
    int stride = gridDim.x * blockDim.x;
    float* wt_hr = wbase;
    float* wt_lr = wbase + 16384;
    float* wtE = wbase + 32768;
    float* wtE2 = wbase + 51200;
    for (int i = tid; i < 16384; i += stride) {
        int ci = i >> 6, co = i & 63;
        wt_hr[i] = Whr[co * 256 + ci];
        wt_lr[i] = Wlr[co * 256 + ci];
    }
    for (int i = tid; i < 18432; i += stride) {
        int r = i >> 5, co = i & 31;
        int ci = r / 9, t = r % 9;
        wtE[i] = (co < 25) ? Wenc[(co * 64 + ci) * 9 + t] : 0.f;
    }
    for (int i = tid; i < 9216; i += stride) {
        int r = i >> 4, co = i & 15;
        int ci = r / 9, t = r % 9;
        wtE2[i] = (co < 9) ? Wenc2[(co * 64 + ci) * 9 + t] : 0.f;
    }
}

// ------------- 1x1 conv core: uniform (n, co-group) from blockIdx; weights -> s_load -------
template <int CH>
__device__ __forceinline__ void conv1x1_core(const float* __restrict x,
                                             const float* __restrict wt,
                                             const float* __restrict bias,
                                             float* __restrict y, int HWp, int n, int g,
                                             int px) {
    int co0 = g * CH;  // uniform
    const float* xb = x + (size_t)n * 256 * HWp + px;
    const float* w0 = wt + co0;  // uniform base
    float acc[CH];
#pragma unroll
    for (int j = 0; j < CH; j++) acc[j] = 0.f;
#pragma unroll 8
    for (int ci = 0; ci < 256; ci++) {
        float xv = xb[(size_t)ci * HWp];
        const float* wrow = w0 + ci * 64;  // uniform
#pragma unroll
        for (int j = 0; j < CH; j++) acc[j] = fmaf(wrow[j], xv, acc[j]);
    }
#pragma unroll
    for (int j = 0; j < CH; j++)
        y[((size_t)(n * 64 + co0 + j)) * HWp + px] = acc[j] + bias[co0 + j];
}

// merged conv1x1 for hr (CH=16, 4 groups) and lr (CH=8, 8 groups)
__global__ void conv1x1_all_k(const float* __restrict hr, const float* __restrict lrf,
                              const float* __restrict wt_hr, const float* __restrict wt_lr,
                              const float* __restrict bhr, const float* __restrict blr,
                              float* __restrict chf, float* __restrict clf, int N) {
    const int HRB = (HWH / 256) * N * 4;  // 512 for N=2
    int b = blockIdx.x;
    if (b < HRB) {
        int pxb = b % (HWH / 256);
        int n = (b / (HWH / 256)) % N;
        int g = b / ((HWH / 256) * N);
        int px = pxb * 256 + threadIdx.x;
        conv1x1_core<16>(hr, wt_hr, bhr, chf, HWH, n, g, px);
    } else {
        int b2 = b - HRB;
        int pxb = b2 % (HWL / 256);
        int n = (b2 / (HWL / 256)) % N;
        int g = b2 / ((HWL / 256) * N);
        int px = pxb * 256 + threadIdx.x;
        conv1x1_core<8>(lrf, wt_lr, blr, clf, HWL, n, g, px);
    }
}

// ---------------- 3x3 conv core pad=1, uniform (n,g) ----------------
template <int COUT, int CH, int PAD, int LOG2W, int HH, int WW>
__device__ __forceinline__ void conv3x3_core(const float* __restrict x,
                                             const float* __restrict wt,
                                             const float* __restrict bias,
                                             float* __restrict y, int n, int g, int px) {
    constexpr int HWp = HH * WW;
    int co0 = g * CH;  // uniform
    int yy = px >> LOG2W, xx = px & (WW - 1);
    int offs[9];
    bool val[9];
#pragma unroll
    for (int t = 0; t < 9; t++) {
        int sy = yy + t / 3 - 1, sx = xx + t % 3 - 1;
        bool ok = (sy >= 0 && sy < HH && sx >= 0 && sx < WW);
        offs[t] = ok ? sy * WW + sx : 0;
        val[t] = ok;
    }
    float acc[CH];
#pragma unroll
    for (int j = 0; j < CH; j++) acc[j] = 0.f;
    const float* xb = x + (size_t)n * 64 * HWp;
    for (int ci = 0; ci < 64; ci++) {
        const float* xc = xb + (size_t)ci * HWp;
#pragma unroll
        for (int t = 0; t < 9; t++) {
            float xv = val[t] ? xc[offs[t]] : 0.f;
            const float* wrow = wt + (ci * 9 + t) * PAD + co0;  // uniform
#pragma unroll
            for (int j = 0; j < CH; j++) acc[j] = fmaf(wrow[j], xv, acc[j]);
        }
    }
#pragma unroll
    for (int j = 0; j < CH; j++) {
        int co = co0 + j;
        if (co < COUT) y[((size_t)(n * COUT + co)) * HWp + px] = acc[j] + bias[co];
    }
}

// C: 3x3 chf -> mask_hr_hr (9ch, 3 groups of 3)
__global__ void conv3x3_C_k(const float* __restrict chf, const float* __restrict wtE2,
                            const float* __restrict benc2, float* __restrict m_hrhr, int N) {
    int b = blockIdx.x;
    int pxb = b % 64;
    int n = (b / 64) % N;
    int g = b / (64 * N);
    conv3x3_core<9, 3, 16, 7, WH, WH>(chf, wtE2, benc2, m_hrhr, n, g,
                                      pxb * 256 + (int)threadIdx.x);
}

// merged F (chf2->m_lrhr, 25ch hi-res), G (clf->g_out, 25ch lo-res), K (clf->k_out, 9ch lo-res)
__global__ void conv3x3_FGK_k(const float* __restrict chf2, const float* __restrict clf,
                              const float* __restrict wtE, const float* __restrict wtE2,
                              const float* __restrict benc, const float* __restrict benc2,
                              float* __restrict m_lrhr, float* __restrict g_out,
                              float* __restrict k_out, int N) {
    const int FB = 64 * N * 5, GB = 16 * N * 5;
    int b = blockIdx.x;
    if (b < FB) {
        int pxb = b % 64;
        int n = (b / 64) % N;
        int g = b / (64 * N);
        conv3x3_core<25, 5, 32, 7, WH, WH>(chf2, wtE, benc, m_lrhr, n, g,
                                           pxb * 256 + (int)threadIdx.x);
    } else if (b < FB + GB) {
        int b2 = b - FB;
        int pxb = b2 % 16;
        int n = (b2 / 16) % N;
        int g = b2 / (16 * N);
        conv3x3_core<25, 5, 32, 6, WL, WL>(clf, wtE, benc, g_out, n, g,
                                           pxb * 256 + (int)threadIdx.x);
    } else {
        int b2 = b - FB - GB;
        int pxb = b2 % 16;
        int n = (b2 / 16) % N;
        int g = b2 / (16 * N);
        conv3x3_core<9, 3, 16, 6, WL, WL>(clf, wtE2, benc2, k_out, n, g,
                                          pxb * 256 + (int)threadIdx.x);
    }
}

// ------- stage D+E: chf2 = 2*chf - carafe(chf, norm(mask_hr_hr), k=3, up=1), 8 ch-groups -------
__global__ void fuse_de_k(const float* __restrict chf, const float* __restrict mask,
                          float* __restrict chf2, int N) {
    int b = blockIdx.x;
    int pxb = b % 64;
    int n = (b / 64) % N;
    int c0 = (b / (64 * N)) * 8;
    int px = pxb * 256 + threadIdx.x;
    int yy = px >> 7, xx = px & 127;
    float m[9];
    normalize_mask<3>(mask + (size_t)n * 9 * HWH + px, HWH, m);
    int offs[9];
    float mm[9];
#pragma unroll
    for (int t = 0; t < 9; t++) {
        int sy = yy + t / 3 - 1, sx = xx + t % 3 - 1;
        bool ok = (sy >= 0 && sy < WH && sx >= 0 && sx < WH);
        offs[t] = ok ? sy * WH + sx : 0;
        mm[t] = ok ? m[t] : 0.f;
    }
    const float* cb = chf + (size_t)n * 64 * HWH;
    float* ob = chf2 + (size_t)n * 64 * HWH + px;
#pragma unroll
    for (int c = c0; c < c0 + 8; c++) {
        const float* xc = cb + (size_t)c * HWH;
        float s = 0.f, center = 0.f;
#pragma unroll
        for (int t = 0; t < 9; t++) {
            float xv = xc[offs[t]];
            if (t == 4) center = xv;
            s = fmaf(mm[t], xv, s);
        }
        ob[(size_t)c * HWH] = 2.f * center - s;
    }
}

// ---- stage H+I: mask_lr = mask_lr_hr + carafe(g_out, norm(mask_lr_hr), k=5, up=2) ----
__global__ void fuse_hi_k(const float* __restrict mlrhr, const float* __restrict g,
                          float* __restrict mask_lr, int N) {
    int b = blockIdx.x;
    int pxb = b % 64;
    int n = (b / 64) % N;
    int co0 = (b / (64 * N)) * 5;
    int px = pxb * 256 + threadIdx.x;
    int Y = px >> 7, X = px & 127;
    int h = Y >> 1, w = X >> 1;
    const float* mb = mlrhr + (size_t)n * 25 * HWH + px;
    float m[25];
    normalize_mask<5>(mb, HWH, m);
    float acc[5];
#pragma unroll
    for (int j = 0; j < 5; j++) acc[j] = 0.f;
    const float* gb = g + ((size_t)n * 25 + co0) * HWL;
    for (int k = 0; k < 25; k++) {
        int sy = h + k / 5 - 2, sx = w + k % 5 - 2;
        if (sy >= 0 && sy < WL && sx >= 0 && sx < WL) {
            int off = sy * WL + sx;
            float mk = m[k];
#pragma unroll
            for (int j = 0; j < 5; j++)
                acc[j] = fmaf(mk, gb[(size_t)j * HWL + off], acc[j]);
        }
    }
#pragma unroll
    for (int j = 0; j < 5; j++)
        mask_lr[((size_t)(n * 25 + co0 + j)) * HWH + px] =
            mb[(size_t)(co0 + j) * HWH] + acc[j];
}

// ---------------- normalize mask_lr -> out0 (== m_lo2 == mask_lr_n) ----------------
__global__ void norm25_k(const float* __restrict mask_lr, float* __restrict out0, int N) {
    int b = blockIdx.x;
    int pxb = b % 64;
    int n = b / 64;
    int px = pxb * 256 + threadIdx.x;
    float m[25];
    normalize_mask<5>(mask_lr + (size_t)n * 25 * HWH + px, HWH, m);
#pragma unroll
    for (int k = 0; k < 25; k++) out0[((size_t)(n * 25 + k)) * HWH + px] = m[k];
}

// ---- stage L: mask_hr = mask_hr_hr + carafe(k_out, out0, k=5, up=2); 3 co-groups of 3 ----
__global__ void fuse_l_k(const float* __restrict m_n, const float* __restrict kf,
                         const float* __restrict mhrhr, float* __restrict mask_hr, int N) {
    int b = blockIdx.x;
    int pxb = b % 64;
    int n = (b / 64) % N;
    int co0 = (b / (64 * N)) * 3;
    int px = pxb * 256 + threadIdx.x;
    int Y = px >> 7, X = px & 127;
    int h = Y >> 1, w = X >> 1;
    float m[25];
#pragma unroll
    for (int k = 0; k < 25; k++) m[k] = m_n[((size_t)(n * 25 + k)) * HWH + px];
    float acc[3];
#pragma unroll
    for (int j = 0; j < 3; j++) acc[j] = 0.f;
    const float* kb = kf + ((size_t)n * 9 + co0) * HWL;
    for (int k = 0; k < 25; k++) {
        int sy = h + k / 5 - 2, sx = w + k % 5 - 2;
        if (sy >= 0 && sy < WL && sx >= 0 && sx < WL) {
            int off = sy * WL + sx;
            float mk = m[k];
#pragma unroll
            for (int j = 0; j < 3; j++)
                acc[j] = fmaf(mk, kb[(size_t)j * HWL + off], acc[j]);
        }
    }
#pragma unroll
    for (int j = 0; j < 3; j++)
        mask_hr[((size_t)(n * 9 + co0 + j)) * HWH + px] =
            mhrhr[((size_t)(n * 9 + co0 + j)) * HWH + px] + acc[j];
}

// ------------- hr_out = 2*hr - carafe(hr, norm(mask_hr), k=3, up=1) -> O1; 32 ch-groups -----
__global__ void hr_out_k(const float* __restrict mask_hr, const float* __restrict hr,
                         float* __restrict out1, int N) {
    int b = blockIdx.x;
    int pxb = b % 64;
    int n = (b / 64) % N;
    int c0 = (b / (64 * N)) * 8;
    int px = pxb * 256 + threadIdx.x;
    int yy = px >> 7, xx = px & 127;
    float m[9];
    normalize_mask<3>(mask_hr + (size_t)n * 9 * HWH + px, HWH, m);
    int offs[9];
    float mm[9];
#pragma unroll
    for (int t = 0; t < 9; t++) {
        int sy = yy + t / 3 - 1, sx = xx + t % 3 - 1;
        bool ok = (sy >= 0 && sy < WH && sx >= 0 && sx < WH);
        offs[t] = ok ? sy * WH + sx : 0;
        mm[t] = ok ? m[t] : 0.f;
    }
    const float* hb = hr + (size_t)n * 256 * HWH;
    float* ob = out1 + (size_t)n * 256 * HWH + px;
#pragma unroll
    for (int c = c0; c < c0 + 8; c++) {
        const float* hc = hb + (size_t)c * HWH;
        float s = 0.f, center = 0.f;
#pragma unroll
        for (int t = 0; t < 9; t++) {
            float xv = hc[offs[t]];
            if (t == 4) center = xv;
            s = fmaf(mm[t], xv, s);
        }
        ob[(size_t)c * HWH] = 2.f * center - s;
    }
}

// ------- lr_out = carafe(lr_feat, out0, k=5, up=2) -> O2 (runs LAST) -------
// thread = (n, 8-ch group, output px-PAIR). X-even/odd share the same source window.
__global__ void lr_out_k(const float* __restrict m_n, const float* __restrict lr,
                         float* __restrict out2, int N) {
    int b = blockIdx.x;
    int pxb = b & 31;                 // 32 pair-blocks per n
    int n = (b >> 5) % N;
    int c0 = (b / (32 * N)) * 8;
    int pairIdx = pxb * 256 + threadIdx.x;  // [0, 8192)
    int Y = pairIdx >> 6, wp = pairIdx & 63;
    int px = Y * WH + 2 * wp;
    int h = Y >> 1, w = wp;
    float mm0[25], mm1[25];
    int offs[25];
#pragma unroll
    for (int k = 0; k < 25; k++) {
        float2 mk = *reinterpret_cast<const float2*>(m_n + ((size_t)(n * 25 + k)) * HWH + px);
        int sy = h + k / 5 - 2, sx = w + k % 5 - 2;
        bool ok = (sy >= 0 && sy < WL && sx >= 0 && sx < WL);
        offs[k] = ok ? sy * WL + sx : 0;
        mm0[k] = ok ? mk.x : 0.f;
        mm1[k] = ok ? mk.y : 0.f;
    }
    const float* lb = lr + ((size_t)n * 256 + c0) * HWL;
    float* ob = out2 + ((size_t)n * 256 + c0) * HWH + px;
#pragma unroll 2
    for (int c = 0; c < 8; c++) {
        const float* lc = lb + (size_t)c * HWL;
        float s0 = 0.f, s1 = 0.f;
#pragma unroll
        for (int k = 0; k < 25; k++) {
            float v = lc[offs[k]];
            s0 = fmaf(mm0[k], v, s0);
            s1 = fmaf(mm1[k], v, s1);
        }
        *reinterpret_cast<float2*>(ob + (size_t)c * HWH) = make_float2(s0, s1);
    }
}

extern "C" void kernel_launch(void* const* d_in, const int* in_sizes, int n_in, void* d_out,
                              int out_size, void* d_ws, size_t ws_size, hipStream_t stream) {
    const float* hr = (const float*)d_in[0];
    const float* lr = (const float*)d_in[1];
    const float* Whr = (const float*)d_in[2];
    const float* bhr = (const float*)d_in[3];
    const float* Wlr = (const float*)d_in[4];
    const float* blr = (const float*)d_in[5];
    const float* Wenc = (const float*)d_in[6];
    const float* benc = (const float*)d_in[7];
    const float* Wenc2 = (const float*)d_in[8];
    const float* benc2 = (const float*)d_in[9];
    float* out = (float*)d_out;
    const int B = in_sizes[0] / (256 * HWH);  // 2
    (void)d_ws; (void)ws_size;

    float* out0 = out;                           // B*25*HWH  (final: mask_lr_n)
    float* O1 = out + (size_t)B * 25 * HWH;      // B*256*HWH (final: hr_out)
    float* O2 = O1 + (size_t)B * 256 * HWH;      // B*256*HWH (final: lr_out)

    // --- scratch inside O2 (dead before lr_out_k overwrites O2) ---
    float* wbase = O2;                                // 60416 floats of weights
    float* wt_hr = wbase;                             // 16384
    float* wt_lr = wbase + 16384;                     // 16384
    float* wtE = wbase + 32768;                       // 18432
    float* wtE2 = wbase + 51200;                      // 9216
    float* mask_hr = O2 + 60416;                      // B*9*HWH

    // --- scratch inside O1 (dead before hr_out_k overwrites O1) ---
    float* chf = O1;                                  // B*64*HWH
    float* chf2 = chf + (size_t)B * 64 * HWH;
    float* clf = chf2 + (size_t)B * 64 * HWH;         // B*64*HWL
    float* m_hrhr = clf + (size_t)B * 64 * HWL;       // B*9*HWH
    float* m_lrhr = m_hrhr + (size_t)B * 9 * HWH;     // B*25*HWH
    float* g_out = m_lrhr + (size_t)B * 25 * HWH;     // B*25*HWL
    float* k_out = g_out + (size_t)B * 25 * HWL;      // B*9*HWL
    float* mask_lr = k_out + (size_t)B * 9 * HWL;     // B*25*HWH (ends < B*256*HWH)

    prep_w_k<<<64, 256, 0, stream>>>(Whr, Wlr, Wenc, Wenc2, wbase);
    // A+B merged: both 1x1 convs in one dispatch
    conv1x1_all_k<<<64 * B * 4 + 16 * B * 8, 256, 0, stream>>>(hr, lr, wt_hr, wt_lr, bhr,
                                                               blr, chf, clf, B);
    // C: 3x3 chf -> mask_hr_hr
    conv3x3_C_k<<<64 * B * 3, 256, 0, stream>>>(chf, wtE2, benc2, m_hrhr, B);
    // D+E: chf2
    fuse_de_k<<<64 * B * 8, 256, 0, stream>>>(chf, m_hrhr, chf2, B);
    // F+G+K merged
    conv3x3_FGK_k<<<64 * B * 5 + 16 * B * 5 + 16 * B * 3, 256, 0, stream>>>(
        chf2, clf, wtE, wtE2, benc, benc2, m_lrhr, g_out, k_out, B);
    // H+I: mask_lr
    fuse_hi_k<<<64 * B * 5, 256, 0, stream>>>(m_lrhr, g_out, mask_lr, B);
    // J: out0 = normalize(mask_lr)
    norm25_k<<<64 * B, 256, 0, stream>>>(mask_lr, out0, B);
    // L: mask_hr
    fuse_l_k<<<64 * B * 3, 256, 0, stream>>>(out0, k_out, m_hrhr, mask_hr, B);
    // M+O: hr_out -> O1 (32 ch-groups)
    hr_out_k<<<64 * B * 32, 256, 0, stream>>>(mask_hr, hr, O1, B);
    // N: lr_out -> O2 (pair-sharing, 32 ch-groups)
    lr_out_k<<<32 * B * 32, 256, 0, stream>>>(out0, lr, O2, B);
}

// Round 5
// 242.209 us; speedup vs baseline: 4.1708x; 1.5073x over previous
//
#include <hip/hip_runtime.h>

// FreqFusion forward, f32. Shapes fixed: B=2, C=256, CC=64, HR=128x128, LR=64x64.
// Scratch: d_ws unused. Intermediates live inside d_out (see layout in kernel_launch).
#define HWH 16384   // 128*128
#define HWL 4096    // 64*64
#define WH 128
#define WL 64

// ---------------- hamming helpers ----------------
__device__ __forceinline__ float ham3v(int t) {
    const float h[3] = {0.08f, 1.0f, 0.08f};
    return h[t / 3] * h[t % 3];
}
__device__ __forceinline__ float ham5v(int t) {
    const float h[5] = {0.08f, 0.54f, 1.0f, 0.54f, 0.08f};
    return h[t / 5] * h[t % 5];
}

// softmax over K*K ch, *ham, renorm  ==  exp(x-max)*ham / sum(exp(x-max)*ham)
template <int K>
__device__ __forceinline__ void normalize_mask(const float* __restrict src, int stride,
                                               float* m) {
    constexpr int K2 = K * K;
    float mx = -1e30f;
#pragma unroll
    for (int k = 0; k < K2; k++) {
        m[k] = src[(size_t)k * stride];
        mx = fmaxf(mx, m[k]);
    }
    float s = 0.f;
#pragma unroll
    for (int k = 0; k < K2; k++) {
        float hv = (K == 3) ? ham3v(k) : ham5v(k);
        float e = __expf(m[k] - mx) * hv;
        m[k] = e;
        s += e;
    }
    float inv = 1.f / s;
#pragma unroll
    for (int k = 0; k < K2; k++) m[k] *= inv;
}

// ---------------- weight prep: transpose to [ci][co] (co contiguous) ----------------
__global__ void prep_w_k(const float* __restrict Whr, const float* __restrict Wlr,
                         const float* __restrict Wenc, const float* __restrict Wenc2,
                         float* __restrict wbase) {
    int tid = blockIdx.x * blockDim.x + threadIdx.x;
    int stride = gridDim.x * blockDim.x;
    float* wt_hr = wbase;
    float* wt_lr = wbase + 16384;
    float* wtE = wbase + 32768;
    float* wtE2 = wbase + 51200;
    for (int i = tid; i < 16384; i += stride) {
        int ci = i >> 6, co = i & 63;
        wt_hr[i] = Whr[co * 256 + ci];
        wt_lr[i] = Wlr[co * 256 + ci];
    }
    for (int i = tid; i < 18432; i += stride) {
        int r = i >> 5, co = i & 31;
        int ci = r / 9, t = r % 9;
        wtE[i] = (co < 25) ? Wenc[(co * 64 + ci) * 9 + t] : 0.f;
    }
    for (int i = tid; i < 9216; i += stride) {
        int r = i >> 4, co = i & 15;
        int ci = r / 9, t = r % 9;
        wtE2[i] = (co < 9) ? Wenc2[(co * 64 + ci) * 9 + t] : 0.f;
    }
}

// ------------- 1x1 conv core: uniform (n, co-group) from blockIdx; weights -> s_load -------
template <int CH>
__device__ __forceinline__ void conv1x1_core(const float* __restrict x,
                                             const float* __restrict wt,
                                             const float* __restrict bias,
                                             float* __restrict y, int HWp, int n, int g,
                                             int px) {
    int co0 = g * CH;  // uniform
    const float* xb = x + (size_t)n * 256 * HWp + px;
    const float* w0 = wt + co0;  // uniform base
    float acc[CH];
#pragma unroll
    for (int j = 0; j < CH; j++) acc[j] = 0.f;
#pragma unroll 8
    for (int ci = 0; ci < 256; ci++) {
        float xv = xb[(size_t)ci * HWp];
        const float* wrow = w0 + ci * 64;  // uniform
#pragma unroll
        for (int j = 0; j < CH; j++) acc[j] = fmaf(wrow[j], xv, acc[j]);
    }
#pragma unroll
    for (int j = 0; j < CH; j++)
        y[((size_t)(n * 64 + co0 + j)) * HWp + px] = acc[j] + bias[co0 + j];
}

// merged conv1x1 for hr (CH=16, 4 groups) and lr (CH=8, 8 groups)
__global__ void conv1x1_all_k(const float* __restrict hr, const float* __restrict lrf,
                              const float* __restrict wt_hr, const float* __restrict wt_lr,
                              const float* __restrict bhr, const float* __restrict blr,
                              float* __restrict chf, float* __restrict clf, int N) {
    const int HRB = (HWH / 256) * N * 4;  // 512 for N=2
    int b = blockIdx.x;
    if (b < HRB) {
        int pxb = b % (HWH / 256);
        int n = (b / (HWH / 256)) % N;
        int g = b / ((HWH / 256) * N);
        int px = pxb * 256 + threadIdx.x;
        conv1x1_core<16>(hr, wt_hr, bhr, chf, HWH, n, g, px);
    } else {
        int b2 = b - HRB;
        int pxb = b2 % (HWL / 256);
        int n = (b2 / (HWL / 256)) % N;
        int g = b2 / ((HWL / 256) * N);
        int px = pxb * 256 + threadIdx.x;
        conv1x1_core<8>(lrf, wt_lr, blr, clf, HWL, n, g, px);
    }
}

// ---------------- 3x3 conv core pad=1, uniform (n,g) ----------------
template <int COUT, int CH, int PAD, int LOG2W, int HH, int WW>
__device__ __forceinline__ void conv3x3_core(const float* __restrict x,
                                             const float* __restrict wt,
                                             const float* __restrict bias,
                                             float* __restrict y, int n, int g, int px) {
    constexpr int HWp = HH * WW;
    int co0 = g * CH;  // uniform
    int yy = px >> LOG2W, xx = px & (WW - 1);
    int offs[9];
    bool val[9];
#pragma unroll
    for (int t = 0; t < 9; t++) {
        int sy = yy + t / 3 - 1, sx = xx + t % 3 - 1;
        bool ok = (sy >= 0 && sy < HH && sx >= 0 && sx < WW);
        offs[t] = ok ? sy * WW + sx : 0;
        val[t] = ok;
    }
    float acc[CH];
#pragma unroll
    for (int j = 0; j < CH; j++) acc[j] = 0.f;
    const float* xb = x + (size_t)n * 64 * HWp;
    for (int ci = 0; ci < 64; ci++) {
        const float* xc = xb + (size_t)ci * HWp;
#pragma unroll
        for (int t = 0; t < 9; t++) {
            float xv = val[t] ? xc[offs[t]] : 0.f;
            const float* wrow = wt + (ci * 9 + t) * PAD + co0;  // uniform
#pragma unroll
            for (int j = 0; j < CH; j++) acc[j] = fmaf(wrow[j], xv, acc[j]);
        }
    }
#pragma unroll
    for (int j = 0; j < CH; j++) {
        int co = co0 + j;
        if (co < COUT) y[((size_t)(n * COUT + co)) * HWp + px] = acc[j] + bias[co];
    }
}

// C: 3x3 chf -> mask_hr_hr (9ch, 3 groups of 3)
__global__ void conv3x3_C_k(const float* __restrict chf, const float* __restrict wtE2,
                            const float* __restrict benc2, float* __restrict m_hrhr, int N) {
    int b = blockIdx.x;
    int pxb = b % 64;
    int n = (b / 64) % N;
    int g = b / (64 * N);
    conv3x3_core<9, 3, 16, 7, WH, WH>(chf, wtE2, benc2, m_hrhr, n, g,
                                      pxb * 256 + (int)threadIdx.x);
}

// merged F (chf2->m_lrhr, 25ch hi-res), G (clf->g_out, 25ch lo-res), K (clf->k_out, 9ch lo-res)
__global__ void conv3x3_FGK_k(const float* __restrict chf2, const float* __restrict clf,
                              const float* __restrict wtE, const float* __restrict wtE2,
                              const float* __restrict benc, const float* __restrict benc2,
                              float* __restrict m_lrhr, float* __restrict g_out,
                              float* __restrict k_out, int N) {
    const int FB = 64 * N * 5, GB = 16 * N * 5;
    int b = blockIdx.x;
    if (b < FB) {
        int pxb = b % 64;
        int n = (b / 64) % N;
        int g = b / (64 * N);
        conv3x3_core<25, 5, 32, 7, WH, WH>(chf2, wtE, benc, m_lrhr, n, g,
                                           pxb * 256 + (int)threadIdx.x);
    } else if (b < FB + GB) {
        int b2 = b - FB;
        int pxb = b2 % 16;
        int n = (b2 / 16) % N;
        int g = b2 / (16 * N);
        conv3x3_core<25, 5, 32, 6, WL, WL>(clf, wtE, benc, g_out, n, g,
                                           pxb * 256 + (int)threadIdx.x);
    } else {
        int b2 = b - FB - GB;
        int pxb = b2 % 16;
        int n = (b2 / 16) % N;
        int g = b2 / (16 * N);
        conv3x3_core<9, 3, 16, 6, WL, WL>(clf, wtE2, benc2, k_out, n, g,
                                          pxb * 256 + (int)threadIdx.x);
    }
}

// ------- stage D+E: chf2 = 2*chf - carafe(chf, norm(mask_hr_hr), k=3, up=1), 8 ch-groups -------
__global__ void fuse_de_k(const float* __restrict chf, const float* __restrict mask,
                          float* __restrict chf2, int N) {
    int b = blockIdx.x;
    int pxb = b % 64;
    int n = (b / 64) % N;
    int c0 = (b / (64 * N)) * 8;
    int px = pxb * 256 + threadIdx.x;
    int yy = px >> 7, xx = px & 127;
    float m[9];
    normalize_mask<3>(mask + (size_t)n * 9 * HWH + px, HWH, m);
    int offs[9];
    float mm[9];
#pragma unroll
    for (int t = 0; t < 9; t++) {
        int sy = yy + t / 3 - 1, sx = xx + t % 3 - 1;
        bool ok = (sy >= 0 && sy < WH && sx >= 0 && sx < WH);
        offs[t] = ok ? sy * WH + sx : 0;
        mm[t] = ok ? m[t] : 0.f;
    }
    const float* cb = chf + (size_t)n * 64 * HWH;
    float* ob = chf2 + (size_t)n * 64 * HWH + px;
#pragma unroll
    for (int c = c0; c < c0 + 8; c++) {
        const float* xc = cb + (size_t)c * HWH;
        float s = 0.f, center = 0.f;
#pragma unroll
        for (int t = 0; t < 9; t++) {
            float xv = xc[offs[t]];
            if (t == 4) center = xv;
            s = fmaf(mm[t], xv, s);
        }
        ob[(size_t)c * HWH] = 2.f * center - s;
    }
}

// ---- stage H+I: mask_lr = mask_lr_hr + carafe(g_out, norm(mask_lr_hr), k=5, up=2) ----
__global__ void fuse_hi_k(const float* __restrict mlrhr, const float* __restrict g,
                          float* __restrict mask_lr, int N) {
    int b = blockIdx.x;
    int pxb = b % 64;
    int n = (b / 64) % N;
    int co0 = (b / (64 * N)) * 5;
    int px = pxb * 256 + threadIdx.x;
    int Y = px >> 7, X = px & 127;
    int h = Y >> 1, w = X >> 1;
    const float* mb = mlrhr + (size_t)n * 25 * HWH + px;
    float m[25];
    normalize_mask<5>(mb, HWH, m);
    float acc[5];
#pragma unroll
    for (int j = 0; j < 5; j++) acc[j] = 0.f;
    const float* gb = g + ((size_t)n * 25 + co0) * HWL;
    for (int k = 0; k < 25; k++) {
        int sy = h + k / 5 - 2, sx = w + k % 5 - 2;
        if (sy >= 0 && sy < WL && sx >= 0 && sx < WL) {
            int off = sy * WL + sx;
            float mk = m[k];
#pragma unroll
            for (int j = 0; j < 5; j++)
                acc[j] = fmaf(mk, gb[(size_t)j * HWL + off], acc[j]);
        }
    }
#pragma unroll
    for (int j = 0; j < 5; j++)
        mask_lr[((size_t)(n * 25 + co0 + j)) * HWH + px] =
            mb[(size_t)(co0 + j) * HWH] + acc[j];
}

// ---------------- normalize mask_lr -> out0 (== m_lo2 == mask_lr_n) ----------------
__global__ void norm25_k(const float* __restrict mask_lr, float* __restrict out0, int N) {
    int b = blockIdx.x;
    int pxb = b % 64;
    int n = b / 64;
    int px = pxb * 256 + threadIdx.x;
    float m[25];
    normalize_mask<5>(mask_lr + (size_t)n * 25 * HWH + px, HWH, m);
#pragma unroll
    for (int k = 0; k < 25; k++) out0[((size_t)(n * 25 + k)) * HWH + px] = m[k];
}

// ---- stage L: mask_hr = mask_hr_hr + carafe(k_out, out0, k=5, up=2); 3 co-groups of 3 ----
__global__ void fuse_l_k(const float* __restrict m_n, const float* __restrict kf,
                         const float* __restrict mhrhr, float* __restrict mask_hr, int N) {
    int b = blockIdx.x;
    int pxb = b % 64;
    int n = (b / 64) % N;
    int co0 = (b / (64 * N)) * 3;
    int px = pxb * 256 + threadIdx.x;
    int Y = px >> 7, X = px & 127;
    int h = Y >> 1, w = X >> 1;
    float m[25];
#pragma unroll
    for (int k = 0; k < 25; k++) m[k] = m_n[((size_t)(n * 25 + k)) * HWH + px];
    float acc[3];
#pragma unroll
    for (int j = 0; j < 3; j++) acc[j] = 0.f;
    const float* kb = kf + ((size_t)n * 9 + co0) * HWL;
    for (int k = 0; k < 25; k++) {
        int sy = h + k / 5 - 2, sx = w + k % 5 - 2;
        if (sy >= 0 && sy < WL && sx >= 0 && sx < WL) {
            int off = sy * WL + sx;
            float mk = m[k];
#pragma unroll
            for (int j = 0; j < 3; j++)
                acc[j] = fmaf(mk, kb[(size_t)j * HWL + off], acc[j]);
        }
    }
#pragma unroll
    for (int j = 0; j < 3; j++)
        mask_hr[((size_t)(n * 9 + co0 + j)) * HWH + px] =
            mhrhr[((size_t)(n * 9 + co0 + j)) * HWH + px] + acc[j];
}

// ------------- hr_out = 2*hr - carafe(hr, norm(mask_hr), k=3, up=1) -> O1 -------------
// LDS-tiled: block = (n, 8-ch group, 8-row tile). Src tile 8ch x 10r x 132c zero-filled.
#define HRCHG 8
__global__ __launch_bounds__(256) void hr_out_k(const float* __restrict mask_hr,
                                                const float* __restrict hr,
                                                float* __restrict out1, int N) {
    __shared__ float tile[HRCHG][10][132];  // 42240 B
    int b = blockIdx.x;
    int yt = b & 15;          // 16 y-tiles of 8 rows
    int g = (b >> 4) & 31;    // 32 ch-groups of 8
    int n = b >> 9;
    int y0 = yt * 8;
    int c0 = g * HRCHG;
    const float* hb = hr + ((size_t)n * 256 + c0) * HWH;
    for (int e = threadIdx.x; e < HRCHG * 10 * 132; e += 256) {
        int c = e / (10 * 132);
        int rem = e % (10 * 132);
        int r = rem / 132, col = rem % 132;
        int y = y0 + r - 1, x = col - 1;
        float v = 0.f;
        if (y >= 0 && y < WH && x >= 0 && x < WH) v = hb[(size_t)c * HWH + y * WH + x];
        tile[c][r][col] = v;
    }
    __syncthreads();
    float* ob = out1 + ((size_t)n * 256 + c0) * HWH;
#pragma unroll
    for (int i = 0; i < 4; i++) {
        int lp = threadIdx.x + 256 * i;  // [0,1024): local px in 8x128 tile
        int ly = lp >> 7, lx = lp & 127;
        int px = (y0 + ly) * WH + lx;
        float m[9];
        normalize_mask<3>(mask_hr + (size_t)n * 9 * HWH + px, HWH, m);
        for (int c = 0; c < HRCHG; c++) {
            float center = tile[c][ly + 1][lx + 1];
            float s = 0.f;
#pragma unroll
            for (int t = 0; t < 9; t++)
                s = fmaf(m[t], tile[c][ly + t / 3][lx + t % 3], s);
            ob[(size_t)c * HWH + px] = 2.f * center - s;
        }
    }
}

// ------- lr_out = carafe(lr_feat, out0, k=5, up=2) -> O2 (runs LAST) -------
// LDS-tiled: block = (n, 16-ch group, 16-row output tile -> 8+4 src rows).
// Thread owns output 2x2 quads (shared source window); 25 LDS reads serve 4 outputs x ch.
#define LRCHG 16
__global__ __launch_bounds__(256, 1) void lr_out_k(const float* __restrict m_n,
                                                   const float* __restrict lr,
                                                   float* __restrict out2, int N) {
    __shared__ float tile[LRCHG][12][68];  // 52224 B
    int b = blockIdx.x;
    int yt = b & 7;           // 8 y-tiles of 16 output rows
    int g = (b >> 3) & 15;    // 16 ch-groups of 16
    int n = b >> 7;
    int y0 = yt * 16;
    int hbase = y0 >> 1;
    int c0 = g * LRCHG;
    const float* lrb = lr + ((size_t)n * 256 + c0) * HWL;
    for (int e = threadIdx.x; e < LRCHG * 12 * 68; e += 256) {
        int c = e / (12 * 68);
        int rem = e % (12 * 68);
        int r = rem / 68, col = rem % 68;
        int h = hbase + r - 2, w = col - 2;
        float v = 0.f;
        if (h >= 0 && h < WL && w >= 0 && w < WL) v = lrb[(size_t)c * HWL + h * WL + w];
        tile[c][r][col] = v;
    }
    __syncthreads();
    const float* mb = m_n + (size_t)n * 25 * HWH;
    float* ob = out2 + ((size_t)n * 256 + c0) * HWH;
#pragma unroll
    for (int i = 0; i < 2; i++) {
        int q = threadIdx.x + 256 * i;  // [0,512): quad = 2x2 out px @ (y0+2qy, 2qx)
        int qy = q >> 6, qx = q & 63;
        int Y0 = y0 + 2 * qy;
        int X0 = 2 * qx;
        float2 mk0[25], mk1[25];
#pragma unroll
        for (int k = 0; k < 25; k++) {
            mk0[k] = *(const float2*)(mb + (size_t)k * HWH + Y0 * WH + X0);
            mk1[k] = *(const float2*)(mb + (size_t)k * HWH + (Y0 + 1) * WH + X0);
        }
        for (int c = 0; c < LRCHG; c++) {
            float a00 = 0.f, a01 = 0.f, a10 = 0.f, a11 = 0.f;
#pragma unroll
            for (int k = 0; k < 25; k++) {
                float v = tile[c][qy + k / 5][qx + k % 5];
                a00 = fmaf(mk0[k].x, v, a00);
                a01 = fmaf(mk0[k].y, v, a01);
                a10 = fmaf(mk1[k].x, v, a10);
                a11 = fmaf(mk1[k].y, v, a11);
            }
            float* op = ob + (size_t)c * HWH + (size_t)Y0 * WH + X0;
            *(float2*)op = make_float2(a00, a01);
            *(float2*)(op + WH) = make_float2(a10, a11);
        }
    }
}

extern "C" void kernel_launch(void* const* d_in, const int* in_sizes, int n_in, void* d_out,
                              int out_size, void* d_ws, size_t ws_size, hipStream_t stream) {
    const float* hr = (const float*)d_in[0];
    const float* lr = (const float*)d_in[1];
    const float* Whr = (const float*)d_in[2];
    const float* bhr = (const float*)d_in[3];
    const float* Wlr = (const float*)d_in[4];
    const float* blr = (const float*)d_in[5];
    const float* Wenc = (const float*)d_in[6];
    const float* benc = (const float*)d_in[7];
    const float* Wenc2 = (const float*)d_in[8];
    const float* benc2 = (const float*)d_in[9];
    float* out = (float*)d_out;
    const int B = in_sizes[0] / (256 * HWH);  // 2
    (void)d_ws; (void)ws_size;

    float* out0 = out;                           // B*25*HWH  (final: mask_lr_n)
    float* O1 = out + (size_t)B * 25 * HWH;      // B*256*HWH (final: hr_out)
    float* O2 = O1 + (size_t)B * 256 * HWH;      // B*256*HWH (final: lr_out)

    // --- scratch inside O2 (dead before lr_out_k overwrites O2) ---
    float* wbase = O2;                                // 60416 floats of weights
    float* wt_hr = wbase;                             // 16384
    float* wt_lr = wbase + 16384;                     // 16384
    float* wtE = wbase + 32768;                       // 18432
    float* wtE2 = wbase + 51200;                      // 9216
    float* mask_hr = O2 + 60416;                      // B*9*HWH

    // --- scratch inside O1 (dead before hr_out_k overwrites O1) ---
    float* chf = O1;                                  // B*64*HWH
    float* chf2 = chf + (size_t)B * 64 * HWH;
    float* clf = chf2 + (size_t)B * 64 * HWH;         // B*64*HWL
    float* m_hrhr = clf + (size_t)B * 64 * HWL;       // B*9*HWH
    float* m_lrhr = m_hrhr + (size_t)B * 9 * HWH;     // B*25*HWH
    float* g_out = m_lrhr + (size_t)B * 25 * HWH;     // B*25*HWL
    float* k_out = g_out + (size_t)B * 25 * HWL;      // B*9*HWL
    float* mask_lr = k_out + (size_t)B * 9 * HWL;     // B*25*HWH (ends < B*256*HWH)

    prep_w_k<<<64, 256, 0, stream>>>(Whr, Wlr, Wenc, Wenc2, wbase);
    // A+B merged: both 1x1 convs in one dispatch
    conv1x1_all_k<<<64 * B * 4 + 16 * B * 8, 256, 0, stream>>>(hr, lr, wt_hr, wt_lr, bhr,
                                                               blr, chf, clf, B);
    // C: 3x3 chf -> mask_hr_hr
    conv3x3_C_k<<<64 * B * 3, 256, 0, stream>>>(chf, wtE2, benc2, m_hrhr, B);
    // D+E: chf2
    fuse_de_k<<<64 * B * 8, 256, 0, stream>>>(chf, m_hrhr, chf2, B);
    // F+G+K merged
    conv3x3_FGK_k<<<64 * B * 5 + 16 * B * 5 + 16 * B * 3, 256, 0, stream>>>(
        chf2, clf, wtE, wtE2, benc, benc2, m_lrhr, g_out, k_out, B);
    // H+I: mask_lr
    fuse_hi_k<<<64 * B * 5, 256, 0, stream>>>(m_lrhr, g_out, mask_lr, B);
    // J: out0 = normalize(mask_lr)
    norm25_k<<<64 * B, 256, 0, stream>>>(mask_lr, out0, B);
    // L: mask_hr
    fuse_l_k<<<64 * B * 3, 256, 0, stream>>>(out0, k_out, m_hrhr, mask_hr, B);
    // M+O: hr_out -> O1 (LDS-tiled; 2*32*16 = N*512 blocks)
    hr_out_k<<<B * 512, 256, 0, stream>>>(mask_hr, hr, O1, B);
    // N: lr_out -> O2 (LDS-tiled; 2*16*8 = N*128 blocks)
    lr_out_k<<<B * 128, 256, 0, stream>>>(out0, lr, O2, B);
}

// Round 6
// 230.001 us; speedup vs baseline: 4.3922x; 1.0531x over previous
//
#include <hip/hip_runtime.h>

// FreqFusion forward, f32. Shapes fixed: B=2, C=256, CC=64, HR=128x128, LR=64x64.
// Scratch: d_ws unused. Intermediates live inside d_out (see layout in kernel_launch).
#define HWH 16384   // 128*128
#define HWL 4096    // 64*64
#define WH 128
#define WL 64

// ---------------- hamming helpers ----------------
__device__ __forceinline__ float ham3v(int t) {
    const float h[3] = {0.08f, 1.0f, 0.08f};
    return h[t / 3] * h[t % 3];
}
__device__ __forceinline__ float ham5v(int t) {
    const float h[5] = {0.08f, 0.54f, 1.0f, 0.54f, 0.08f};
    return h[t / 5] * h[t % 5];
}

// softmax over K*K ch, *ham, renorm  ==  exp(x-max)*ham / sum(exp(x-max)*ham)
template <int K>
__device__ __forceinline__ void normalize_post(float* m) {
    constexpr int K2 = K * K;
    float mx = -1e30f;
#pragma unroll
    for (int k = 0; k < K2; k++) mx = fmaxf(mx, m[k]);
    float s = 0.f;
#pragma unroll
    for (int k = 0; k < K2; k++) {
        float hv = (K == 3) ? ham3v(k) : ham5v(k);
        float e = __expf(m[k] - mx) * hv;
        m[k] = e;
        s += e;
    }
    float inv = 1.f / s;
#pragma unroll
    for (int k = 0; k < K2; k++) m[k] *= inv;
}

template <int K>
__device__ __forceinline__ void normalize_mask(const float* __restrict src, int stride,
                                               float* m) {
#pragma unroll
    for (int k = 0; k < K * K; k++) m[k] = src[(size_t)k * stride];
    normalize_post<K>(m);
}

// normalize over the SUM of two partial buffers
template <int K>
__device__ __forceinline__ void normalize_mask2(const float* __restrict a,
                                                const float* __restrict b, int stride,
                                                float* m) {
#pragma unroll
    for (int k = 0; k < K * K; k++)
        m[k] = a[(size_t)k * stride] + b[(size_t)k * stride];
    normalize_post<K>(m);
}

// ---------------- weight prep: transpose to [ci][co] (co contiguous) ----------------
__global__ void prep_w_k(const float* __restrict Whr, const float* __restrict Wlr,
                         const float* __restrict Wenc, const float* __restrict Wenc2,
                         float* __restrict wbase) {
    int tid = blockIdx.x * blockDim.x + threadIdx.x;
    int stride = gridDim.x * blockDim.x;
    float* wt_hr = wbase;
    float* wt_lr = wbase + 16384;
    float* wtE = wbase + 32768;
    float* wtE2 = wbase + 51200;
    for (int i = tid; i < 16384; i += stride) {
        int ci = i >> 6, co = i & 63;
        wt_hr[i] = Whr[co * 256 + ci];
        wt_lr[i] = Wlr[co * 256 + ci];
    }
    for (int i = tid; i < 18432; i += stride) {
        int r = i >> 5, co = i & 31;
        int ci = r / 9, t = r % 9;
        wtE[i] = (co < 25) ? Wenc[(co * 64 + ci) * 9 + t] : 0.f;
    }
    for (int i = tid; i < 9216; i += stride) {
        int r = i >> 4, co = i & 15;
        int ci = r / 9, t = r % 9;
        wtE2[i] = (co < 9) ? Wenc2[(co * 64 + ci) * 9 + t] : 0.f;
    }
}

// ------------- 1x1 conv core: uniform (n, co-group) from blockIdx; weights -> s_load -------
template <int CH>
__device__ __forceinline__ void conv1x1_core(const float* __restrict x,
                                             const float* __restrict wt,
                                             const float* __restrict bias,
                                             float* __restrict y, int HWp, int n, int g,
                                             int px) {
    int co0 = g * CH;  // uniform
    const float* xb = x + (size_t)n * 256 * HWp + px;
    const float* w0 = wt + co0;  // uniform base
    float acc[CH];
#pragma unroll
    for (int j = 0; j < CH; j++) acc[j] = 0.f;
#pragma unroll 8
    for (int ci = 0; ci < 256; ci++) {
        float xv = xb[(size_t)ci * HWp];
        const float* wrow = w0 + ci * 64;  // uniform
#pragma unroll
        for (int j = 0; j < CH; j++) acc[j] = fmaf(wrow[j], xv, acc[j]);
    }
#pragma unroll
    for (int j = 0; j < CH; j++)
        y[((size_t)(n * 64 + co0 + j)) * HWp + px] = acc[j] + bias[co0 + j];
}

// merged conv1x1 for hr (CH=16, 4 groups) and lr (CH=8, 8 groups)
__global__ void conv1x1_all_k(const float* __restrict hr, const float* __restrict lrf,
                              const float* __restrict wt_hr, const float* __restrict wt_lr,
                              const float* __restrict bhr, const float* __restrict blr,
                              float* __restrict chf, float* __restrict clf, int N) {
    const int HRB = (HWH / 256) * N * 4;  // 512 for N=2
    int b = blockIdx.x;
    if (b < HRB) {
        int pxb = b % (HWH / 256);
        int n = (b / (HWH / 256)) % N;
        int g = b / ((HWH / 256) * N);
        int px = pxb * 256 + threadIdx.x;
        conv1x1_core<16>(hr, wt_hr, bhr, chf, HWH, n, g, px);
    } else {
        int b2 = b - HRB;
        int pxb = b2 % (HWL / 256);
        int n = (b2 / (HWL / 256)) % N;
        int g = b2 / ((HWL / 256) * N);
        int px = pxb * 256 + threadIdx.x;
        conv1x1_core<8>(lrf, wt_lr, blr, clf, HWL, n, g, px);
    }
}

// ---------------- 3x3 conv core pad=1, uniform (n,g); ci range [ci0, ci0+NCI) ----------------
template <int COUT, int CH, int PAD, int LOG2W, int HH, int WW, int NCI>
__device__ __forceinline__ void conv3x3_core(const float* __restrict x,
                                             const float* __restrict wt,
                                             const float* __restrict bias,
                                             float* __restrict y, int n, int g, int px,
                                             int ci0, bool addb) {
    constexpr int HWp = HH * WW;
    int co0 = g * CH;  // uniform
    int yy = px >> LOG2W, xx = px & (WW - 1);
    int offs[9];
    bool val[9];
#pragma unroll
    for (int t = 0; t < 9; t++) {
        int sy = yy + t / 3 - 1, sx = xx + t % 3 - 1;
        bool ok = (sy >= 0 && sy < HH && sx >= 0 && sx < WW);
        offs[t] = ok ? sy * WW + sx : 0;
        val[t] = ok;
    }
    float acc[CH];
#pragma unroll
    for (int j = 0; j < CH; j++) acc[j] = 0.f;
    const float* xb = x + ((size_t)n * 64 + ci0) * HWp;
    const float* wb = wt + (size_t)(ci0 * 9) * PAD + co0;
    for (int ci = 0; ci < NCI; ci++) {
        const float* xc = xb + (size_t)ci * HWp;
#pragma unroll
        for (int t = 0; t < 9; t++) {
            float xv = val[t] ? xc[offs[t]] : 0.f;
            const float* wrow = wb + (ci * 9 + t) * PAD;  // uniform
#pragma unroll
            for (int j = 0; j < CH; j++) acc[j] = fmaf(wrow[j], xv, acc[j]);
        }
    }
#pragma unroll
    for (int j = 0; j < CH; j++) {
        int co = co0 + j;
        if (co < COUT)
            y[((size_t)(n * COUT + co)) * HWp + px] = acc[j] + (addb ? bias[co] : 0.f);
    }
}

// merged: C (chf->m_hrhr partials, ci-split) + G (clf->g_out) + K (clf->k_out)
__global__ void conv3x3_CGK_k(const float* __restrict chf, const float* __restrict clf,
                              const float* __restrict wtE, const float* __restrict wtE2,
                              const float* __restrict benc, const float* __restrict benc2,
                              float* __restrict m_hrhr_pA, float* __restrict m_hrhr_pB,
                              float* __restrict g_out, float* __restrict k_out, int N) {
    const int CB = 64 * N * 3 * 2, GB = 16 * N * 5;
    int b = blockIdx.x;
    if (b < CB) {
        int t = b;
        int pxb = t % 64; t /= 64;
        int n = t % N; t /= N;
        int g = t % 3;
        int s = t / 3;
        conv3x3_core<9, 3, 16, 7, WH, WH, 32>(chf, wtE2, benc2, s ? m_hrhr_pB : m_hrhr_pA,
                                              n, g, pxb * 256 + (int)threadIdx.x, s * 32,
                                              s == 0);
    } else if (b < CB + GB) {
        int t = b - CB;
        int pxb = t % 16; t /= 16;
        int n = t % N;
        int g = t / N;
        conv3x3_core<25, 5, 32, 6, WL, WL, 64>(clf, wtE, benc, g_out, n, g,
                                               pxb * 256 + (int)threadIdx.x, 0, true);
    } else {
        int t = b - CB - GB;
        int pxb = t % 16; t /= 16;
        int n = t % N;
        int g = t / N;
        conv3x3_core<9, 3, 16, 6, WL, WL, 64>(clf, wtE2, benc2, k_out, n, g,
                                              pxb * 256 + (int)threadIdx.x, 0, true);
    }
}

// F: chf2 -> m_lrhr partials (25ch hi-res, 5 co-groups, ci-split)
__global__ void conv3x3_F_k(const float* __restrict chf2, const float* __restrict wtE,
                            const float* __restrict benc, float* __restrict pA,
                            float* __restrict pB, int N) {
    int t = blockIdx.x;
    int pxb = t % 64; t /= 64;
    int n = t % N; t /= N;
    int g = t % 5;
    int s = t / 5;
    conv3x3_core<25, 5, 32, 7, WH, WH, 32>(chf2, wtE, benc, s ? pB : pA, n, g,
                                           pxb * 256 + (int)threadIdx.x, s * 32, s == 0);
}

// ------- stage D+E: chf2 = 2*chf - carafe(chf, norm(m_hrhr), k=3, up=1), 8 ch-groups -------
__global__ void fuse_de_k(const float* __restrict chf, const float* __restrict mA,
                          const float* __restrict mB, float* __restrict chf2, int N) {
    int b = blockIdx.x;
    int pxb = b % 64;
    int n = (b / 64) % N;
    int c0 = (b / (64 * N)) * 8;
    int px = pxb * 256 + threadIdx.x;
    int yy = px >> 7, xx = px & 127;
    float m[9];
    normalize_mask2<3>(mA + (size_t)n * 9 * HWH + px, mB + (size_t)n * 9 * HWH + px, HWH, m);
    int offs[9];
    float mm[9];
#pragma unroll
    for (int t = 0; t < 9; t++) {
        int sy = yy + t / 3 - 1, sx = xx + t % 3 - 1;
        bool ok = (sy >= 0 && sy < WH && sx >= 0 && sx < WH);
        offs[t] = ok ? sy * WH + sx : 0;
        mm[t] = ok ? m[t] : 0.f;
    }
    const float* cb = chf + (size_t)n * 64 * HWH;
    float* ob = chf2 + (size_t)n * 64 * HWH + px;
#pragma unroll
    for (int c = c0; c < c0 + 8; c++) {
        const float* xc = cb + (size_t)c * HWH;
        float s = 0.f, center = 0.f;
#pragma unroll
        for (int t = 0; t < 9; t++) {
            float xv = xc[offs[t]];
            if (t == 4) center = xv;
            s = fmaf(mm[t], xv, s);
        }
        ob[(size_t)c * HWH] = 2.f * center - s;
    }
}

// ---- stage H+I: mask_lr = (m_lrhr) + carafe(g_out, norm(m_lrhr), k=5, up=2) ----
__global__ void fuse_hi_k(const float* __restrict mA, const float* __restrict mB,
                          const float* __restrict g, float* __restrict mask_lr, int N) {
    int b = blockIdx.x;
    int pxb = b % 64;
    int n = (b / 64) % N;
    int co0 = (b / (64 * N)) * 5;
    int px = pxb * 256 + threadIdx.x;
    int Y = px >> 7, X = px & 127;
    int h = Y >> 1, w = X >> 1;
    const float* mbA = mA + (size_t)n * 25 * HWH + px;
    const float* mbB = mB + (size_t)n * 25 * HWH + px;
    float m[25];
    normalize_mask2<5>(mbA, mbB, HWH, m);
    float acc[5];
#pragma unroll
    for (int j = 0; j < 5; j++) acc[j] = 0.f;
    const float* gb = g + ((size_t)n * 25 + co0) * HWL;
    for (int k = 0; k < 25; k++) {
        int sy = h + k / 5 - 2, sx = w + k % 5 - 2;
        if (sy >= 0 && sy < WL && sx >= 0 && sx < WL) {
            int off = sy * WL + sx;
            float mk = m[k];
#pragma unroll
            for (int j = 0; j < 5; j++)
                acc[j] = fmaf(mk, gb[(size_t)j * HWL + off], acc[j]);
        }
    }
#pragma unroll
    for (int j = 0; j < 5; j++)
        mask_lr[((size_t)(n * 25 + co0 + j)) * HWH + px] =
            mbA[(size_t)(co0 + j) * HWH] + mbB[(size_t)(co0 + j) * HWH] + acc[j];
}

// ---------------- normalize mask_lr -> out0 (== m_lo2 == mask_lr_n); 64-thr blocks ----------
__global__ void norm25_k(const float* __restrict mask_lr, float* __restrict out0, int N) {
    int b = blockIdx.x;
    int pxb = b % 256;           // 256 px-blocks of 64
    int n = b / 256;
    int px = pxb * 64 + threadIdx.x;
    float m[25];
    normalize_mask<5>(mask_lr + (size_t)n * 25 * HWH + px, HWH, m);
#pragma unroll
    for (int k = 0; k < 25; k++) out0[((size_t)(n * 25 + k)) * HWH + px] = m[k];
}

// ---- stage L: mask_hr = (m_hrhr) + carafe(k_out, out0, k=5, up=2); 3 co-groups of 3 ----
__global__ void fuse_l_k(const float* __restrict m_n, const float* __restrict kf,
                         const float* __restrict mhA, const float* __restrict mhB,
                         float* __restrict mask_hr, int N) {
    int b = blockIdx.x;
    int pxb = b % 64;
    int n = (b / 64) % N;
    int co0 = (b / (64 * N)) * 3;
    int px = pxb * 256 + threadIdx.x;
    int Y = px >> 7, X = px & 127;
    int h = Y >> 1, w = X >> 1;
    float m[25];
#pragma unroll
    for (int k = 0; k < 25; k++) m[k] = m_n[((size_t)(n * 25 + k)) * HWH + px];
    float acc[3];
#pragma unroll
    for (int j = 0; j < 3; j++) acc[j] = 0.f;
    const float* kb = kf + ((size_t)n * 9 + co0) * HWL;
    for (int k = 0; k < 25; k++) {
        int sy = h + k / 5 - 2, sx = w + k % 5 - 2;
        if (sy >= 0 && sy < WL && sx >= 0 && sx < WL) {
            int off = sy * WL + sx;
            float mk = m[k];
#pragma unroll
            for (int j = 0; j < 3; j++)
                acc[j] = fmaf(mk, kb[(size_t)j * HWL + off], acc[j]);
        }
    }
#pragma unroll
    for (int j = 0; j < 3; j++)
        mask_hr[((size_t)(n * 9 + co0 + j)) * HWH + px] =
            mhA[((size_t)(n * 9 + co0 + j)) * HWH + px] +
            mhB[((size_t)(n * 9 + co0 + j)) * HWH + px] + acc[j];
}

// ------------- hr_out = 2*hr - carafe(hr, norm(mask_hr), k=3, up=1) -> O1 -------------
// LDS-tiled: block = (n, 8-ch group, 8-row tile). Src tile 8ch x 10r x 132c zero-filled.
#define HRCHG 8
__global__ __launch_bounds__(256) void hr_out_k(const float* __restrict mask_hr,
                                                const float* __restrict hr,
                                                float* __restrict out1, int N) {
    __shared__ float tile[HRCHG][10][132];  // 42240 B
    int b = blockIdx.x;
    int yt = b & 15;          // 16 y-tiles of 8 rows
    int g = (b >> 4) & 31;    // 32 ch-groups of 8
    int n = b >> 9;
    int y0 = yt * 8;
    int c0 = g * HRCHG;
    const float* hb = hr + ((size_t)n * 256 + c0) * HWH;
    for (int e = threadIdx.x; e < HRCHG * 10 * 132; e += 256) {
        int c = e / (10 * 132);
        int rem = e % (10 * 132);
        int r = rem / 132, col = rem % 132;
        int y = y0 + r - 1, x = col - 1;
        float v = 0.f;
        if (y >= 0 && y < WH && x >= 0 && x < WH) v = hb[(size_t)c * HWH + y * WH + x];
        tile[c][r][col] = v;
    }
    __syncthreads();
    float* ob = out1 + ((size_t)n * 256 + c0) * HWH;
#pragma unroll
    for (int i = 0; i < 4; i++) {
        int lp = threadIdx.x + 256 * i;  // [0,1024): local px in 8x128 tile
        int ly = lp >> 7, lx = lp & 127;
        int px = (y0 + ly) * WH + lx;
        float m[9];
        normalize_mask<3>(mask_hr + (size_t)n * 9 * HWH + px, HWH, m);
        for (int c = 0; c < HRCHG; c++) {
            float center = tile[c][ly + 1][lx + 1];
            float s = 0.f;
#pragma unroll
            for (int t = 0; t < 9; t++)
                s = fmaf(m[t], tile[c][ly + t / 3][lx + t % 3], s);
            ob[(size_t)c * HWH + px] = 2.f * center - s;
        }
    }
}

// ------- lr_out = carafe(lr_feat, out0, k=5, up=2) -> O2 (runs LAST) -------
#define LRCHG 16
__global__ __launch_bounds__(256, 1) void lr_out_k(const float* __restrict m_n,
                                                   const float* __restrict lr,
                                                   float* __restrict out2, int N) {
    __shared__ float tile[LRCHG][12][68];  // 52224 B
    int b = blockIdx.x;
    int yt = b & 7;           // 8 y-tiles of 16 output rows
    int g = (b >> 3) & 15;    // 16 ch-groups of 16
    int n = b >> 7;
    int y0 = yt * 16;
    int hbase = y0 >> 1;
    int c0 = g * LRCHG;
    const float* lrb = lr + ((size_t)n * 256 + c0) * HWL;
    for (int e = threadIdx.x; e < LRCHG * 12 * 68; e += 256) {
        int c = e / (12 * 68);
        int rem = e % (12 * 68);
        int r = rem / 68, col = rem % 68;
        int h = hbase + r - 2, w = col - 2;
        float v = 0.f;
        if (h >= 0 && h < WL && w >= 0 && w < WL) v = lrb[(size_t)c * HWL + h * WL + w];
        tile[c][r][col] = v;
    }
    __syncthreads();
    const float* mb = m_n + (size_t)n * 25 * HWH;
    float* ob = out2 + ((size_t)n * 256 + c0) * HWH;
#pragma unroll
    for (int i = 0; i < 2; i++) {
        int q = threadIdx.x + 256 * i;  // [0,512): quad = 2x2 out px @ (y0+2qy, 2qx)
        int qy = q >> 6, qx = q & 63;
        int Y0 = y0 + 2 * qy;
        int X0 = 2 * qx;
        float2 mk0[25], mk1[25];
#pragma unroll
        for (int k = 0; k < 25; k++) {
            mk0[k] = *(const float2*)(mb + (size_t)k * HWH + Y0 * WH + X0);
            mk1[k] = *(const float2*)(mb + (size_t)k * HWH + (Y0 + 1) * WH + X0);
        }
        for (int c = 0; c < LRCHG; c++) {
            float a00 = 0.f, a01 = 0.f, a10 = 0.f, a11 = 0.f;
#pragma unroll
            for (int k = 0; k < 25; k++) {
                float v = tile[c][qy + k / 5][qx + k % 5];
                a00 = fmaf(mk0[k].x, v, a00);
                a01 = fmaf(mk0[k].y, v, a01);
                a10 = fmaf(mk1[k].x, v, a10);
                a11 = fmaf(mk1[k].y, v, a11);
            }
            float* op = ob + (size_t)c * HWH + (size_t)Y0 * WH + X0;
            *(float2*)op = make_float2(a00, a01);
            *(float2*)(op + WH) = make_float2(a10, a11);
        }
    }
}

extern "C" void kernel_launch(void* const* d_in, const int* in_sizes, int n_in, void* d_out,
                              int out_size, void* d_ws, size_t ws_size, hipStream_t stream) {
    const float* hr = (const float*)d_in[0];
    const float* lr = (const float*)d_in[1];
    const float* Whr = (const float*)d_in[2];
    const float* bhr = (const float*)d_in[3];
    const float* Wlr = (const float*)d_in[4];
    const float* blr = (const float*)d_in[5];
    const float* Wenc = (const float*)d_in[6];
    const float* benc = (const float*)d_in[7];
    const float* Wenc2 = (const float*)d_in[8];
    const float* benc2 = (const float*)d_in[9];
    float* out = (float*)d_out;
    const int B = in_sizes[0] / (256 * HWH);  // 2
    (void)d_ws; (void)ws_size;

    float* out0 = out;                           // B*25*HWH  (final: mask_lr_n)
    float* O1 = out + (size_t)B * 25 * HWH;      // B*256*HWH (final: hr_out)
    float* O2 = O1 + (size_t)B * 256 * HWH;      // B*256*HWH (final: lr_out)

    // --- scratch inside O2 (dead before lr_out_k overwrites O2) ---
    float* wbase = O2;                                // 60416 floats of weights
    float* wt_hr = wbase;                             // 16384
    float* wt_lr = wbase + 16384;                     // 16384
    float* wtE = wbase + 32768;                       // 18432
    float* wtE2 = wbase + 51200;                      // 9216
    float* mask_hr = O2 + 60416;                      // B*9*HWH

    // --- scratch inside O1 (dead before hr_out_k overwrites O1); total 8,044,544 < 8,388,608
    float* chf = O1;                                  // B*64*HWH = 2097152
    float* chf2 = chf + (size_t)B * 64 * HWH;         // 2097152
    float* clf = chf2 + (size_t)B * 64 * HWH;         // B*64*HWL = 524288
    float* m_hrhr_pA = clf + (size_t)B * 64 * HWL;    // B*9*HWH = 294912
    float* m_hrhr_pB = m_hrhr_pA + (size_t)B * 9 * HWH;   // 294912
    float* m_lrhr_pA = m_hrhr_pB + (size_t)B * 9 * HWH;   // B*25*HWH = 819200
    float* m_lrhr_pB = m_lrhr_pA + (size_t)B * 25 * HWH;  // 819200
    float* g_out = m_lrhr_pB + (size_t)B * 25 * HWH;  // B*25*HWL = 204800
    float* k_out = g_out + (size_t)B * 25 * HWL;      // B*9*HWL = 73728
    float* mask_lr = k_out + (size_t)B * 9 * HWL;     // B*25*HWH = 819200

    prep_w_k<<<64, 256, 0, stream>>>(Whr, Wlr, Wenc, Wenc2, wbase);
    // A+B merged: both 1x1 convs in one dispatch
    conv1x1_all_k<<<64 * B * 4 + 16 * B * 8, 256, 0, stream>>>(hr, lr, wt_hr, wt_lr, bhr,
                                                               blr, chf, clf, B);
    // C (ci-split partials) + G + K merged: only needs conv1x1 outputs
    conv3x3_CGK_k<<<64 * B * 6 + 16 * B * 5 + 16 * B * 3, 256, 0, stream>>>(
        chf, clf, wtE, wtE2, benc, benc2, m_hrhr_pA, m_hrhr_pB, g_out, k_out, B);
    // D+E: chf2 (normalizes m_hrhr partial sum)
    fuse_de_k<<<64 * B * 8, 256, 0, stream>>>(chf, m_hrhr_pA, m_hrhr_pB, chf2, B);
    // F: chf2 -> m_lrhr partials (ci-split, 1280 blocks)
    conv3x3_F_k<<<64 * B * 10, 256, 0, stream>>>(chf2, wtE, benc, m_lrhr_pA, m_lrhr_pB, B);
    // H+I: mask_lr (sums m_lrhr partials)
    fuse_hi_k<<<64 * B * 5, 256, 0, stream>>>(m_lrhr_pA, m_lrhr_pB, g_out, mask_lr, B);
    // J: out0 = normalize(mask_lr); 64-thread blocks for full-chip spread
    norm25_k<<<256 * B, 64, 0, stream>>>(mask_lr, out0, B);
    // L: mask_hr (sums m_hrhr partials)
    fuse_l_k<<<64 * B * 3, 256, 0, stream>>>(out0, k_out, m_hrhr_pA, m_hrhr_pB, mask_hr, B);
    // M+O: hr_out -> O1 (LDS-tiled)
    hr_out_k<<<B * 512, 256, 0, stream>>>(mask_hr, hr, O1, B);
    // N: lr_out -> O2 (LDS-tiled)
    lr_out_k<<<B * 128, 256, 0, stream>>>(out0, lr, O2, B);
}